// Round 5
// baseline (691.592 us; speedup 1.0000x reference)
//
#include <hip/hip_runtime.h>

// RallyNet latent-SDE, round 5.
// 512 blocks x 512 threads, 8 batch rows/block -> 2 blocks/CU (16 waves/CU).
// k_sde: 3 barriers/step. P3: waves 0-1 compute f AND h for the same cols ->
// in-register barrier-free Euler-Maruyama update (g-gather only on 2 waves).
// Projection runs in P1 (waves 4-5). y in LDS (f32 + f16 A-tile).
// k_gru: 1 barrier/step, weights pinned in registers, ctx straight from
// D-fragments into the d_out alias. g-net via PWL table built in d_ws.

#define TT 100
#define BB 4096
#define DD 32
#define LL 32
#define CC 64
#define HH 128
#define GROW 260

typedef _Float16 h1;
typedef _Float16 h2 __attribute__((ext_vector_type(2)));
typedef _Float16 f16x8 __attribute__((ext_vector_type(8)));
typedef float f32x4 __attribute__((ext_vector_type(4)));

#define MFMA(a, b, c) __builtin_amdgcn_mfma_f32_16x16x32_f16(a, b, c, 0, 0, 0)
#define PIN(x) asm volatile("" : "+v"(x))

__device__ __forceinline__ float sigm(float x) {
  return 1.0f / (1.0f + __expf(-x));
}
__device__ __forceinline__ float tanh_(float x) {
  float xc = fminf(fmaxf(x, -15.0f), 15.0f);
  float e = __expf(2.0f * xc);
  return (e - 1.0f) / (e + 1.0f);
}
__device__ __forceinline__ float splus(float x) {
  float t = __logf(1.0f + __expf(fminf(x, 15.0f)));
  return x > 15.0f ? x : t;
}

// B-fragment of row-major W[N][K] tile (n0,k0): lane l reg j ->
// B[k0+(l>>4)*8+j][n0+(l&15)]
__device__ __forceinline__ f16x8 bfrag(const float* __restrict__ W, int K,
                                       int n0, int k0, int lane) {
  const float* p = W + (size_t)(n0 + (lane & 15)) * K + k0 + ((lane >> 4) << 3);
  f16x8 r;
#pragma unroll
  for (int j = 0; j < 8; ++j) r[j] = (h1)p[j];
  return r;
}

// A-fragment from LDS row-major tile (ld f16/row, rows 16B-aligned)
__device__ __forceinline__ f16x8 afrag(const h1* base, int ld, int k0,
                                       int lane) {
  return *(const f16x8*)(base + (size_t)(lane & 15) * ld + k0 +
                         ((lane >> 4) << 3));
}

// ---------------- g-table build: 32 blocks x 320 threads ----------------
__global__ __launch_bounds__(320) void k_gtab(
    const float* __restrict__ gW1, const float* __restrict__ gb1,
    const float* __restrict__ gW2, const float* __restrict__ gb2,
    float* __restrict__ gtab) {
  const int l = blockIdx.x;
  const int e = threadIdx.x;
  if (e >= 257) return;
  const float yv = -12.f + (float)e * (24.f / 256.f);
  const float* w1 = gW1 + l * HH;
  const float* bb = gb1 + l * HH;
  const float* w2 = gW2 + l * HH;
  float a = 0.f;
#pragma unroll 4
  for (int h = 0; h < HH; ++h)
    a = fmaf(splus(fmaf(yv, w1[h], bb[h])), w2[h], a);
  gtab[l * GROW + e] = sigm(a + gb2[l]);
}

// ---------------- Kernel 1: GRU + encoder, 1 barrier/step ----------------
__global__ __launch_bounds__(512, 4) void k_gru(
    const float* __restrict__ xs, const float* __restrict__ Wih,
    const float* __restrict__ Whh, const float* __restrict__ bih,
    const float* __restrict__ bhh, const float* __restrict__ encW,
    const float* __restrict__ encb, h1* __restrict__ ctx16) {
  __shared__ alignas(16) h1 sH[2][16][136];
  __shared__ alignas(16) h1 sX[2][16][40];

  const int tid = threadIdx.x;
  const int lane = tid & 63, w = tid >> 6;
  const int b0 = blockIdx.x * 8;  // 8 batch rows per block
  const int coln = lane & 15, row4 = (lane >> 4) << 2;

  f16x8 wIH[3], wHH[3][4], wE[4];
#pragma unroll
  for (int g = 0; g < 3; ++g) {
    wIH[g] = bfrag(Wih, DD, 128 * g + 16 * w, 0, lane);
#pragma unroll
    for (int kt = 0; kt < 4; ++kt)
      wHH[g][kt] = bfrag(Whh, HH, 128 * g + 16 * w, 32 * kt, lane);
  }
  if (w >= 4) {
#pragma unroll
    for (int kt = 0; kt < 4; ++kt)
      wE[kt] = bfrag(encW, HH, 16 * (w - 4), 32 * kt, lane);
  }

  const int m = 16 * w + coln;
  const float b_r = bih[m] + bhh[m];
  const float b_z = bih[128 + m] + bhh[128 + m];
  const float b_ni = bih[256 + m];
  const float b_nh = bhh[256 + m];
  const int ccE = (w >= 4) ? 16 * (w - 4) + coln : 0;
  const float bE = (w >= 4) ? encb[ccE] : 0.f;

  // zero h buffer 0 and both x buffers (rows 8-15 stay zero forever)
  for (int i = tid; i < 16 * 136; i += 512) (&sH[0][0][0])[i] = (h1)0.0f;
  for (int i = tid; i < 2 * 16 * 40; i += 512) (&sX[0][0][0])[i] = (h1)0.0f;
  __syncthreads();
  if (tid < 256) sX[0][tid >> 5][tid & 31] = (h1)xs[(size_t)b0 * DD + tid];
  float xHold =
      (tid < 256) ? xs[(size_t)1 * BB * DD + (size_t)b0 * DD + tid] : 0.f;
  float hold[4] = {0.f, 0.f, 0.f, 0.f};
  __syncthreads();

  for (int t = 0; t < TT; ++t) {
    const int cur = t & 1;
    const int tf = (t + 2 < TT) ? (t + 2) : (TT - 1);
    const float xFly =
        (tid < 256) ? xs[(size_t)tf * BB * DD + (size_t)b0 * DD + tid] : 0.f;

#pragma unroll
    for (int g = 0; g < 3; ++g) {
      PIN(wIH[g]);
#pragma unroll
      for (int kt = 0; kt < 4; ++kt) PIN(wHH[g][kt]);
    }
    if (w >= 4) {
#pragma unroll
      for (int kt = 0; kt < 4; ++kt) PIN(wE[kt]);
    }

    f16x8 ax = afrag(&sX[cur][0][0], 40, 0, lane);
    f32x4 aR{0, 0, 0, 0}, aZ{0, 0, 0, 0}, aNI{0, 0, 0, 0}, aNH{0, 0, 0, 0};
    aR = MFMA(ax, wIH[0], aR);
    aZ = MFMA(ax, wIH[1], aZ);
    aNI = MFMA(ax, wIH[2], aNI);
#pragma unroll
    for (int kt = 0; kt < 4; ++kt) {
      f16x8 ah = afrag(&sH[cur][0][0], 136, 32 * kt, lane);
      aR = MFMA(ah, wHH[0][kt], aR);
      aZ = MFMA(ah, wHH[1][kt], aZ);
      aNH = MFMA(ah, wHH[2][kt], aNH);
    }
#pragma unroll
    for (int j = 0; j < 4; ++j) {
      float rg = sigm(aR[j] + b_r);
      float zg = sigm(aZ[j] + b_z);
      float ng = tanh_(aNI[j] + b_ni + rg * (aNH[j] + b_nh));
      float hn = (1.0f - zg) * ng + zg * hold[j];
      hold[j] = hn;
      sH[cur ^ 1][row4 + j][m] = (h1)hn;
    }
    if (tid < 256) sX[cur ^ 1][tid >> 5][tid & 31] = (h1)xHold;
    __syncthreads();  // the only barrier per step

    if (w >= 4) {
      f32x4 aE{0, 0, 0, 0};
#pragma unroll
      for (int kt = 0; kt < 4; ++kt)
        aE = MFMA(afrag(&sH[cur ^ 1][0][0], 136, 32 * kt, lane), wE[kt], aE);
      if (lane < 32) {  // rows 0..7 only
#pragma unroll
        for (int j = 0; j < 4; ++j)
          ctx16[((size_t)t * BB + b0 + row4 + j) * CC + ccE] = (h1)(aE[j] + bE);
      }
    }
    xHold = xFly;
  }
}

// ---------------- Kernel 2: z0 + SDE scan + projection ----------------
__global__ __launch_bounds__(512, 4) void k_sde(
    const float* __restrict__ ts, const float* __restrict__ eps0,
    const float* __restrict__ noise, const float* __restrict__ qz0W,
    const float* __restrict__ qz0b, const float* __restrict__ fW1,
    const float* __restrict__ fb1, const float* __restrict__ fW2,
    const float* __restrict__ fb2, const float* __restrict__ fW3,
    const float* __restrict__ fb3, const float* __restrict__ hW1,
    const float* __restrict__ hb1, const float* __restrict__ hW2,
    const float* __restrict__ hb2, const float* __restrict__ hW3,
    const float* __restrict__ hb3, const float* __restrict__ projW,
    const float* __restrict__ projb, const float* __restrict__ gtab,
    const h1* __restrict__ ctx16, float* __restrict__ out) {
  __shared__ alignas(16) h1 sC[2][16][72];    // ctx f16 (rows 8-15 zero)
  __shared__ alignas(16) h1 sY16[2][16][40];  // y f16 A-tile (rows 8-15 zero)
  __shared__ alignas(16) h1 sA1[16][136], sB1[16][136];
  __shared__ alignas(16) h1 sA2[16][136], sB2[16][136];
  __shared__ alignas(16) float sY32[2][8][36];
  __shared__ alignas(16) float sN[2][8][36];
  __shared__ float sG[32][GROW];
  __shared__ float sDt[TT], sSq[TT];
  __shared__ float sLq[8][36];

  const int tid = threadIdx.x;
  const int lane = tid & 63, w = tid >> 6;
  const int b0 = blockIdx.x * 8;
  const int coln = lane & 15, row4 = (lane >> 4) << 2;
  const int sr = tid >> 5, sc = tid & 31;
  const int cc = 16 * w + coln;

  // zero f16 state tiles (rows 8-15 must be finite forever)
  for (int i = tid; i < 2 * 16 * 72; i += 512) (&sC[0][0][0])[i] = (h1)0.0f;
  for (int i = tid; i < 2 * 16 * 40; i += 512) (&sY16[0][0][0])[i] = (h1)0.0f;
  if (tid < TT - 1) {
    float d = ts[tid + 1] - ts[tid];
    sDt[tid] = d;
    sSq[tid] = __fsqrt_rn(d);
  }
  for (int i = tid; i < 32 * GROW; i += 512) (&sG[0][0])[i] = gtab[i];

  // register-resident weight fragments
  f16x8 wF1[3], wH1v, wF2[4], wH2[4], wF3[4], wH3[4], wPj;
#pragma unroll
  for (int kt = 0; kt < 3; ++kt) wF1[kt] = bfrag(fW1, 96, 16 * w, 32 * kt, lane);
  wH1v = bfrag(hW1, 32, 16 * w, 0, lane);
#pragma unroll
  for (int kt = 0; kt < 4; ++kt) {
    wF2[kt] = bfrag(fW2, HH, 16 * w, 32 * kt, lane);
    wH2[kt] = bfrag(hW2, HH, 16 * w, 32 * kt, lane);
  }
  float bF3 = 0.f, bH3 = 0.f, bPj = 0.f;
  int ccp = 0;
  if (w < 2) {
#pragma unroll
    for (int kt = 0; kt < 4; ++kt) {
      wF3[kt] = bfrag(fW3, HH, 16 * w, 32 * kt, lane);
      wH3[kt] = bfrag(hW3, HH, 16 * w, 32 * kt, lane);
    }
    bF3 = fb3[cc];
    bH3 = hb3[cc];
  } else if (w == 4 || w == 5) {
    ccp = 16 * (w - 4) + coln;
    wPj = bfrag(projW, LL, 16 * (w - 4), 0, lane);
    bPj = projb[ccp];
  }
  const float bF1 = fb1[cc], bH1 = hb1[cc], bF2 = fb2[cc], bH2 = hb2[cc];
  __syncthreads();  // zeros visible

  // stage ctx[0], noise[0] (rows 0..7)
  if (tid < 256) {
    *(h2*)&sC[0][sr][2 * sc] =
        *(const h2*)(ctx16 + (size_t)(b0 + sr) * CC + 2 * sc);
    sN[0][sr][sc] = noise[(size_t)(b0 + sr) * LL + sc];
  }
  __syncthreads();

  // z0 = mean + exp(logstd)*eps0
  if (tid < 256) {
    float m0 = qz0b[sc], s0 = qz0b[32 + sc];
    const float* qm = qz0W + sc * 64;
    const float* qs = qz0W + (32 + sc) * 64;
#pragma unroll 4
    for (int k = 0; k < 64; ++k) {
      float cv = (float)sC[0][sr][k];
      m0 = fmaf(qm[k], cv, m0);
      s0 = fmaf(qs[k], cv, s0);
    }
    float z = fmaf(__expf(s0), eps0[(size_t)(b0 + sr) * LL + sc], m0);
    sY32[0][sr][sc] = z;
    sY16[0][sr][sc] = (h1)z;
  }
  float lqv[4] = {0.f, 0.f, 0.f, 0.f};
  __syncthreads();

  for (int t = 0; t < TT - 1; ++t) {
    const int cur = t & 1;
    // prefetch ctx[t+1], noise[t+1] (staged to LDS in P2)
    h2 cpre{(h1)0, (h1)0};
    float npre = 0.f;
    if (tid < 256) {
      cpre = *(const h2*)(ctx16 + ((size_t)(t + 1) * BB + b0 + sr) * CC + 2 * sc);
      const int tn = (t + 1 < TT - 1) ? (t + 1) : (TT - 2);
      npre = noise[((size_t)tn * BB + b0 + sr) * LL + sc];
    }

#pragma unroll
    for (int kt = 0; kt < 3; ++kt) PIN(wF1[kt]);
    PIN(wH1v);
#pragma unroll
    for (int kt = 0; kt < 4; ++kt) { PIN(wF2[kt]); PIN(wH2[kt]); }
    if (w < 2) {
#pragma unroll
      for (int kt = 0; kt < 4; ++kt) { PIN(wF3[kt]); PIN(wH3[kt]); }
    } else if (w == 4 || w == 5) {
      PIN(wPj);
    }

    // ---- P1: a1/b1; waves 4-5 also project zs[t] ----
    {
      f16x8 aY = afrag(&sY16[cur][0][0], 40, 0, lane);
      f16x8 aC0 = afrag(&sC[cur][0][0], 72, 0, lane);
      f16x8 aC1 = afrag(&sC[cur][0][0], 72, 32, lane);
      f32x4 aF{0, 0, 0, 0}, aH{0, 0, 0, 0};
      aF = MFMA(aY, wF1[0], aF);
      aF = MFMA(aC0, wF1[1], aF);
      aF = MFMA(aC1, wF1[2], aF);
      aH = MFMA(aY, wH1v, aH);
#pragma unroll
      for (int j = 0; j < 4; ++j) {
        sA1[row4 + j][cc] = (h1)splus(aF[j] + bF1);
        sB1[row4 + j][cc] = (h1)splus(aH[j] + bH1);
      }
      if (w == 4 || w == 5) {
        f32x4 ap{0, 0, 0, 0};
        ap = MFMA(aY, wPj, ap);
        if (lane < 32) {
#pragma unroll
          for (int j = 0; j < 4; ++j)
            out[((size_t)t * BB + b0 + row4 + j) * DD + ccp] = ap[j] + bPj;
        }
      }
    }
    __syncthreads();  // BAR1

    // ---- P2: a2/b2; stage prefetched ctx/noise ----
    {
      f32x4 aF{0, 0, 0, 0}, aH{0, 0, 0, 0};
#pragma unroll
      for (int kt = 0; kt < 4; ++kt) {
        aF = MFMA(afrag(&sA1[0][0], 136, 32 * kt, lane), wF2[kt], aF);
        aH = MFMA(afrag(&sB1[0][0], 136, 32 * kt, lane), wH2[kt], aH);
      }
#pragma unroll
      for (int j = 0; j < 4; ++j) {
        sA2[row4 + j][cc] = (h1)splus(aF[j] + bF2);
        sB2[row4 + j][cc] = (h1)splus(aH[j] + bH2);
      }
    }
    if (tid < 256) {
      *(h2*)&sC[cur ^ 1][sr][2 * sc] = cpre;
      sN[cur ^ 1][sr][sc] = npre;
    }
    __syncthreads();  // BAR2

    // ---- P3: waves 0-1 compute f AND h for their 16 cols, then update ----
    if (w < 2) {
      f32x4 aF{0, 0, 0, 0}, aH{0, 0, 0, 0};
#pragma unroll
      for (int kt = 0; kt < 4; ++kt) {
        aF = MFMA(afrag(&sA2[0][0], 136, 32 * kt, lane), wF3[kt], aF);
        aH = MFMA(afrag(&sB2[0][0], 136, 32 * kt, lane), wH3[kt], aH);
      }
      if (lane < 32) {  // valid rows 0..7
        const float dtv = sDt[t], sqdt = sSq[t];
        const float* g = sG[cc];
#pragma unroll
        for (int j = 0; j < 4; ++j) {
          const int row = row4 + j;
          const float f = aF[j] + bF3;
          const float hd = aH[j] + bH3;
          const float yt = sY32[cur][row][cc];
          float p = fminf(fmaxf(fmaf(yt, 32.f / 3.f, 128.f), 0.f), 255.999f);
          const int i = (int)p;
          const float fr = p - (float)i;
          const float gv = fmaf(g[i + 1] - g[i], fr, g[i]);
          const float uv = (f - hd) / gv;
          lqv[j] = fmaf(0.5f * uv * uv, dtv, lqv[j]);
          const float ynew = fmaf(f, dtv, yt) + gv * sqdt * sN[cur][row][cc];
          sY32[cur ^ 1][row][cc] = ynew;
          sY16[cur ^ 1][row][cc] = (h1)ynew;
        }
      }
    }
    __syncthreads();  // BAR3
  }

  // final projection xs_hat[99]
  if (w == 4 || w == 5) {
    f16x8 aY = afrag(&sY16[(TT - 1) & 1][0][0], 40, 0, lane);
    f32x4 ap{0, 0, 0, 0};
    ap = MFMA(aY, wPj, ap);
    if (lane < 32) {
#pragma unroll
      for (int j = 0; j < 4; ++j)
        out[((size_t)(TT - 1) * BB + b0 + row4 + j) * DD + ccp] = ap[j] + bPj;
    }
  }
  // logqp: per-row col-sum
  if (w < 2 && lane < 32) {
#pragma unroll
    for (int j = 0; j < 4; ++j) sLq[row4 + j][cc] = lqv[j];
  }
  __syncthreads();
  if (tid < 8) {
    float s = 0.f;
#pragma unroll
    for (int k = 0; k < 32; ++k) s += sLq[tid][k];
    out[(size_t)TT * BB * DD + b0 + tid] = s;
  }
}

extern "C" void kernel_launch(void* const* d_in, const int* in_sizes, int n_in,
                              void* d_out, int out_size, void* d_ws,
                              size_t ws_size, hipStream_t stream) {
  const float* xs = (const float*)d_in[0];
  const float* ts = (const float*)d_in[1];
  const float* eps0 = (const float*)d_in[2];
  const float* noise = (const float*)d_in[3];
  const float* Wih = (const float*)d_in[4];
  const float* Whh = (const float*)d_in[5];
  const float* bih = (const float*)d_in[6];
  const float* bhh = (const float*)d_in[7];
  const float* encW = (const float*)d_in[8];
  const float* encb = (const float*)d_in[9];
  const float* qz0W = (const float*)d_in[10];
  const float* qz0b = (const float*)d_in[11];
  const float* fW1 = (const float*)d_in[12];
  const float* fb1 = (const float*)d_in[13];
  const float* fW2 = (const float*)d_in[14];
  const float* fb2 = (const float*)d_in[15];
  const float* fW3 = (const float*)d_in[16];
  const float* fb3 = (const float*)d_in[17];
  const float* hW1 = (const float*)d_in[18];
  const float* hb1 = (const float*)d_in[19];
  const float* hW2 = (const float*)d_in[20];
  const float* hb2 = (const float*)d_in[21];
  const float* hW3 = (const float*)d_in[22];
  const float* hb3 = (const float*)d_in[23];
  const float* gW1 = (const float*)d_in[24];
  const float* gb1 = (const float*)d_in[25];
  const float* gW2 = (const float*)d_in[26];
  const float* gb2 = (const float*)d_in[27];
  const float* projW = (const float*)d_in[28];
  const float* projb = (const float*)d_in[29];
  float* out = (float*)d_out;
  h1* ctx16 = (h1*)d_out;      // ctx[t,b,64] f16 aliases xs_hat[t,b,32] f32
  float* gtab = (float*)d_ws;  // 32*260*4 B

  k_gtab<<<32, 320, 0, stream>>>(gW1, gb1, gW2, gb2, gtab);
  k_gru<<<512, 512, 0, stream>>>(xs, Wih, Whh, bih, bhh, encW, encb, ctx16);
  k_sde<<<512, 512, 0, stream>>>(ts, eps0, noise, qz0W, qz0b, fW1, fb1, fW2,
                                 fb2, fW3, fb3, hW1, hb1, hW2, hb2, hW3, hb3,
                                 projW, projb, gtab, ctx16, out);
}

// Round 6
// 464.146 us; speedup vs baseline: 1.4900x; 1.4900x over previous
//
#include <hip/hip_runtime.h>

// RallyNet latent-SDE, round 6.
// 256 blocks x 1024 threads (16 waves/CU = 4/SIMD), 16 batch rows/block.
// Wave specialization splits the same per-step work over 2x waves:
//  k_sde: waves 0-7 f-path, 8-15 h-path + staging; P3: w0-1 f3+h3+update,
//         w2-3 projection. 3 barriers/step. Weights pinned (<=128 VGPR/wave).
//  k_gru: waves 0-7 gates(t) || waves 8-11 encoder(t-1) || 12-15 x-staging,
//         1 barrier/step (enc_t and gates_{t+1} are independent).
// diag-g via PWL table in d_ws. ctx[t,b,:] f16 aliases xs_hat[t,b,:] f32.

#define TT 100
#define BB 4096
#define DD 32
#define LL 32
#define CC 64
#define HH 128
#define GROW 260

typedef _Float16 h1;
typedef _Float16 h2 __attribute__((ext_vector_type(2)));
typedef _Float16 f16x8 __attribute__((ext_vector_type(8)));
typedef float f32x4 __attribute__((ext_vector_type(4)));

#define MFMA(a, b, c) __builtin_amdgcn_mfma_f32_16x16x32_f16(a, b, c, 0, 0, 0)
#define PIN(x) asm volatile("" : "+v"(x))

__device__ __forceinline__ float sigm(float x) {
  return 1.0f / (1.0f + __expf(-x));
}
__device__ __forceinline__ float tanh_(float x) {
  float xc = fminf(fmaxf(x, -15.0f), 15.0f);
  float e = __expf(2.0f * xc);
  return (e - 1.0f) / (e + 1.0f);
}
__device__ __forceinline__ float splus(float x) {
  float t = __logf(1.0f + __expf(fminf(x, 15.0f)));
  return x > 15.0f ? x : t;
}

// B-fragment of row-major W[N][K] tile (n0,k0): lane l reg j ->
// B[k0+(l>>4)*8+j][n0+(l&15)]
__device__ __forceinline__ f16x8 bfrag(const float* __restrict__ W, int K,
                                       int n0, int k0, int lane) {
  const float* p = W + (size_t)(n0 + (lane & 15)) * K + k0 + ((lane >> 4) << 3);
  f16x8 r;
#pragma unroll
  for (int j = 0; j < 8; ++j) r[j] = (h1)p[j];
  return r;
}

// A-fragment from LDS row-major tile (ld f16/row, rows 16B-aligned)
__device__ __forceinline__ f16x8 afrag(const h1* base, int ld, int k0,
                                       int lane) {
  return *(const f16x8*)(base + (size_t)(lane & 15) * ld + k0 +
                         ((lane >> 4) << 3));
}

// ---------------- g-table build: 32 blocks x 320 threads ----------------
__global__ __launch_bounds__(320) void k_gtab(
    const float* __restrict__ gW1, const float* __restrict__ gb1,
    const float* __restrict__ gW2, const float* __restrict__ gb2,
    float* __restrict__ gtab) {
  const int l = blockIdx.x;
  const int e = threadIdx.x;
  if (e >= 257) return;
  const float yv = -12.f + (float)e * (24.f / 256.f);
  const float* w1 = gW1 + l * HH;
  const float* bb = gb1 + l * HH;
  const float* w2 = gW2 + l * HH;
  float a = 0.f;
#pragma unroll 4
  for (int h = 0; h < HH; ++h)
    a = fmaf(splus(fmaf(yv, w1[h], bb[h])), w2[h], a);
  gtab[l * GROW + e] = sigm(a + gb2[l]);
}

// ---------------- Kernel 1: GRU + encoder ----------------
__global__ __launch_bounds__(1024, 4) void k_gru(
    const float* __restrict__ xs, const float* __restrict__ Wih,
    const float* __restrict__ Whh, const float* __restrict__ bih,
    const float* __restrict__ bhh, const float* __restrict__ encW,
    const float* __restrict__ encb, h1* __restrict__ ctx16) {
  __shared__ alignas(16) h1 sH[2][16][136];
  __shared__ alignas(16) h1 sX[2][16][40];

  const int tid = threadIdx.x;
  const int lane = tid & 63, w = tid >> 6;
  const int b0 = blockIdx.x * 16;
  const int coln = lane & 15, row4 = (lane >> 4) << 2;
  const int sidx = tid - 768;  // staging map: waves 12-15 -> 0..255

  f16x8 wIH[3], wHH[3][4], wE[4];
  float b_r = 0, b_z = 0, b_ni = 0, b_nh = 0, bE = 0;
  int m = 0, ccE = 0;
  if (w < 8) {
    m = 16 * w + coln;
#pragma unroll
    for (int g = 0; g < 3; ++g) {
      wIH[g] = bfrag(Wih, DD, 128 * g + 16 * w, 0, lane);
#pragma unroll
      for (int kt = 0; kt < 4; ++kt)
        wHH[g][kt] = bfrag(Whh, HH, 128 * g + 16 * w, 32 * kt, lane);
    }
    b_r = bih[m] + bhh[m];
    b_z = bih[128 + m] + bhh[128 + m];
    b_ni = bih[256 + m];
    b_nh = bhh[256 + m];
  } else if (w < 12) {
    ccE = 16 * (w - 8) + coln;
#pragma unroll
    for (int kt = 0; kt < 4; ++kt)
      wE[kt] = bfrag(encW, HH, 16 * (w - 8), 32 * kt, lane);
    bE = encb[ccE];
  }

  for (int i = tid; i < 16 * 136; i += 1024) (&sH[0][0][0])[i] = (h1)0.0f;
  float2 xHold = {0.f, 0.f};
  if (sidx >= 0 && sidx < 256) {
    const int xr = sidx >> 4, xp = sidx & 15;
    float2 v = *(const float2*)(xs + (size_t)(b0 + xr) * DD + 2 * xp);
    h2 hv;
    hv[0] = (h1)v.x;
    hv[1] = (h1)v.y;
    *(h2*)&sX[0][xr][2 * xp] = hv;
    xHold = *(const float2*)(xs + ((size_t)BB + b0 + xr) * DD + 2 * xp);
  }
  float hold[4] = {0.f, 0.f, 0.f, 0.f};
  __syncthreads();

  // interval t: gates_t (w0-7) || enc_{t-1} (w8-11) || stage x_{t+1} (w12-15)
  for (int t = 0; t <= TT; ++t) {
    const int buf = t & 1;
    if (w < 8) {
      if (t < TT) {
#pragma unroll
        for (int g = 0; g < 3; ++g) {
          PIN(wIH[g]);
#pragma unroll
          for (int kt = 0; kt < 4; ++kt) PIN(wHH[g][kt]);
        }
        f16x8 ax = afrag(&sX[buf][0][0], 40, 0, lane);
        f32x4 aR{0, 0, 0, 0}, aZ{0, 0, 0, 0}, aNI{0, 0, 0, 0}, aNH{0, 0, 0, 0};
        aR = MFMA(ax, wIH[0], aR);
        aZ = MFMA(ax, wIH[1], aZ);
        aNI = MFMA(ax, wIH[2], aNI);
#pragma unroll
        for (int kt = 0; kt < 4; ++kt) {
          f16x8 ah = afrag(&sH[buf][0][0], 136, 32 * kt, lane);
          aR = MFMA(ah, wHH[0][kt], aR);
          aZ = MFMA(ah, wHH[1][kt], aZ);
          aNH = MFMA(ah, wHH[2][kt], aNH);
        }
#pragma unroll
        for (int j = 0; j < 4; ++j) {
          float rg = sigm(aR[j] + b_r);
          float zg = sigm(aZ[j] + b_z);
          float ng = tanh_(aNI[j] + b_ni + rg * (aNH[j] + b_nh));
          float hn = (1.0f - zg) * ng + zg * hold[j];
          hold[j] = hn;
          sH[buf ^ 1][row4 + j][m] = (h1)hn;
        }
      }
    } else if (w < 12) {
      if (t >= 1) {
#pragma unroll
        for (int kt = 0; kt < 4; ++kt) PIN(wE[kt]);
        f32x4 aE{0, 0, 0, 0};
#pragma unroll
        for (int kt = 0; kt < 4; ++kt)
          aE = MFMA(afrag(&sH[buf][0][0], 136, 32 * kt, lane), wE[kt], aE);
#pragma unroll
        for (int j = 0; j < 4; ++j)
          ctx16[((size_t)(t - 1) * BB + b0 + row4 + j) * CC + ccE] =
              (h1)(aE[j] + bE);
      }
    } else {
      if (sidx < 256 && t + 1 < TT) {
        const int xr = sidx >> 4, xp = sidx & 15;
        h2 hv;
        hv[0] = (h1)xHold.x;
        hv[1] = (h1)xHold.y;
        *(h2*)&sX[buf ^ 1][xr][2 * xp] = hv;
        const int tf = (t + 2 < TT) ? (t + 2) : (TT - 1);
        xHold = *(const float2*)(xs + ((size_t)tf * BB + b0 + xr) * DD + 2 * xp);
      }
    }
    __syncthreads();
  }
}

// ---------------- Kernel 2: z0 + SDE scan + projection ----------------
__global__ __launch_bounds__(1024, 4) void k_sde(
    const float* __restrict__ ts, const float* __restrict__ eps0,
    const float* __restrict__ noise, const float* __restrict__ qz0W,
    const float* __restrict__ qz0b, const float* __restrict__ fW1,
    const float* __restrict__ fb1, const float* __restrict__ fW2,
    const float* __restrict__ fb2, const float* __restrict__ fW3,
    const float* __restrict__ fb3, const float* __restrict__ hW1,
    const float* __restrict__ hb1, const float* __restrict__ hW2,
    const float* __restrict__ hb2, const float* __restrict__ hW3,
    const float* __restrict__ hb3, const float* __restrict__ projW,
    const float* __restrict__ projb, const float* __restrict__ gtab,
    const h1* __restrict__ ctx16, float* __restrict__ out) {
  __shared__ alignas(16) h1 sC[2][16][72];
  __shared__ alignas(16) h1 sY16[2][16][40];
  __shared__ alignas(16) h1 sA1[16][136], sB1[16][136];
  __shared__ alignas(16) h1 sA2[16][136], sB2[16][136];
  __shared__ alignas(16) float sY32[2][16][36];
  __shared__ alignas(16) float sN[2][16][36];
  __shared__ float sG[32][GROW];
  __shared__ float sDt[TT], sSq[TT];
  __shared__ float sLq[16][33];

  const int tid = threadIdx.x;
  const int lane = tid & 63, w = tid >> 6;
  const int b0 = blockIdx.x * 16;
  const int coln = lane & 15, row4 = (lane >> 4) << 2;
  const int sidx = tid - 512;  // staging map: waves 8-15 -> 0..511

  // per-wave weights: w<8 f-path, w>=8 h-path; w0-1 also f3/h3; w2-3 proj
  f16x8 wF1[3], wF2[4], wH1v, wH2[4], wF3[4], wH3[4], wPj;
  float bA1 = 0, bA2 = 0, bF3 = 0, bH3 = 0, bPj = 0;
  if (w < 8) {
    const int cc = 16 * w + coln;
#pragma unroll
    for (int kt = 0; kt < 3; ++kt)
      wF1[kt] = bfrag(fW1, 96, 16 * w, 32 * kt, lane);
#pragma unroll
    for (int kt = 0; kt < 4; ++kt)
      wF2[kt] = bfrag(fW2, HH, 16 * w, 32 * kt, lane);
    bA1 = fb1[cc];
    bA2 = fb2[cc];
    if (w < 2) {
#pragma unroll
      for (int kt = 0; kt < 4; ++kt) {
        wF3[kt] = bfrag(fW3, HH, 16 * w, 32 * kt, lane);
        wH3[kt] = bfrag(hW3, HH, 16 * w, 32 * kt, lane);
      }
      bF3 = fb3[16 * w + coln];
      bH3 = hb3[16 * w + coln];
    } else if (w < 4) {
      wPj = bfrag(projW, LL, 16 * (w - 2), 0, lane);
      bPj = projb[16 * (w - 2) + coln];
    }
  } else {
    const int hc = 16 * (w - 8) + coln;
    wH1v = bfrag(hW1, 32, 16 * (w - 8), 0, lane);
#pragma unroll
    for (int kt = 0; kt < 4; ++kt)
      wH2[kt] = bfrag(hW2, HH, 16 * (w - 8), 32 * kt, lane);
    bA1 = hb1[hc];
    bA2 = hb2[hc];
  }

  if (tid < TT - 1) {
    float d = ts[tid + 1] - ts[tid];
    sDt[tid] = d;
    sSq[tid] = __fsqrt_rn(d);
  }
  for (int i = tid; i < 32 * GROW; i += 1024) (&sG[0][0])[i] = gtab[i];
  if (sidx >= 0) {
    const int sr = sidx >> 5, sc = sidx & 31;
    *(h2*)&sC[0][sr][2 * sc] =
        *(const h2*)(ctx16 + (size_t)(b0 + sr) * CC + 2 * sc);
    sN[0][sr][sc] = noise[(size_t)(b0 + sr) * LL + sc];
  }
  __syncthreads();

  // z0 = mean + exp(logstd)*eps0
  if (tid < 512) {
    const int sr = tid >> 5, sc = tid & 31;
    float m0 = qz0b[sc], s0 = qz0b[32 + sc];
    const float* qm = qz0W + sc * 64;
    const float* qs = qz0W + (32 + sc) * 64;
#pragma unroll 4
    for (int k = 0; k < 64; ++k) {
      float cv = (float)sC[0][sr][k];
      m0 = fmaf(qm[k], cv, m0);
      s0 = fmaf(qs[k], cv, s0);
    }
    float z = fmaf(__expf(s0), eps0[(size_t)(b0 + sr) * LL + sc], m0);
    sY32[0][sr][sc] = z;
    sY16[0][sr][sc] = (h1)z;
  }
  float lq[4] = {0.f, 0.f, 0.f, 0.f};
  __syncthreads();

  for (int t = 0; t < TT - 1; ++t) {
    const int cur = t & 1;
    h2 cpre{(h1)0, (h1)0};
    float npre = 0.f;
    if (sidx >= 0) {
      const int sr = sidx >> 5, sc = sidx & 31;
      cpre =
          *(const h2*)(ctx16 + ((size_t)(t + 1) * BB + b0 + sr) * CC + 2 * sc);
      const int tn = (t + 1 < TT - 1) ? (t + 1) : (TT - 2);
      npre = noise[((size_t)tn * BB + b0 + sr) * LL + sc];
    }
    if (w < 8) {
#pragma unroll
      for (int kt = 0; kt < 3; ++kt) PIN(wF1[kt]);
#pragma unroll
      for (int kt = 0; kt < 4; ++kt) PIN(wF2[kt]);
      if (w < 2) {
#pragma unroll
        for (int kt = 0; kt < 4; ++kt) {
          PIN(wF3[kt]);
          PIN(wH3[kt]);
        }
      } else if (w < 4) {
        PIN(wPj);
      }
    } else {
      PIN(wH1v);
#pragma unroll
      for (int kt = 0; kt < 4; ++kt) PIN(wH2[kt]);
    }

    // ---- P1 ----
    if (w < 8) {
      f16x8 aY = afrag(&sY16[cur][0][0], 40, 0, lane);
      f16x8 aC0 = afrag(&sC[cur][0][0], 72, 0, lane);
      f16x8 aC1 = afrag(&sC[cur][0][0], 72, 32, lane);
      f32x4 acc{0, 0, 0, 0};
      acc = MFMA(aY, wF1[0], acc);
      acc = MFMA(aC0, wF1[1], acc);
      acc = MFMA(aC1, wF1[2], acc);
      const int cc = 16 * w + coln;
#pragma unroll
      for (int j = 0; j < 4; ++j) sA1[row4 + j][cc] = (h1)splus(acc[j] + bA1);
    } else {
      f16x8 aY = afrag(&sY16[cur][0][0], 40, 0, lane);
      f32x4 acc{0, 0, 0, 0};
      acc = MFMA(aY, wH1v, acc);
      const int cc = 16 * (w - 8) + coln;
#pragma unroll
      for (int j = 0; j < 4; ++j) sB1[row4 + j][cc] = (h1)splus(acc[j] + bA1);
    }
    __syncthreads();  // BAR1

    // ---- P2 (+ staging on h-waves) ----
    if (w < 8) {
      f32x4 acc{0, 0, 0, 0};
#pragma unroll
      for (int kt = 0; kt < 4; ++kt)
        acc = MFMA(afrag(&sA1[0][0], 136, 32 * kt, lane), wF2[kt], acc);
      const int cc = 16 * w + coln;
#pragma unroll
      for (int j = 0; j < 4; ++j) sA2[row4 + j][cc] = (h1)splus(acc[j] + bA2);
    } else {
      f32x4 acc{0, 0, 0, 0};
#pragma unroll
      for (int kt = 0; kt < 4; ++kt)
        acc = MFMA(afrag(&sB1[0][0], 136, 32 * kt, lane), wH2[kt], acc);
      const int cc = 16 * (w - 8) + coln;
#pragma unroll
      for (int j = 0; j < 4; ++j) sB2[row4 + j][cc] = (h1)splus(acc[j] + bA2);
      const int sr = sidx >> 5, sc = sidx & 31;
      *(h2*)&sC[cur ^ 1][sr][2 * sc] = cpre;
      sN[cur ^ 1][sr][sc] = npre;
    }
    __syncthreads();  // BAR2

    // ---- P3: w0-1 f3+h3+update (tile w); w2-3 projection ----
    if (w < 2) {
      f32x4 aF{0, 0, 0, 0}, aH{0, 0, 0, 0};
#pragma unroll
      for (int kt = 0; kt < 4; ++kt) {
        aF = MFMA(afrag(&sA2[0][0], 136, 32 * kt, lane), wF3[kt], aF);
        aH = MFMA(afrag(&sB2[0][0], 136, 32 * kt, lane), wH3[kt], aH);
      }
      const int col = 16 * w + coln;
      const float dtv = sDt[t], sqdt = sSq[t];
      const float* g = sG[col];
#pragma unroll
      for (int j = 0; j < 4; ++j) {
        const int row = row4 + j;
        const float fv = aF[j] + bF3;
        const float hv = aH[j] + bH3;
        const float yt = sY32[cur][row][col];
        float p = fminf(fmaxf(fmaf(yt, 32.f / 3.f, 128.f), 0.f), 255.999f);
        const int i = (int)p;
        const float fr = p - (float)i;
        const float gv = fmaf(g[i + 1] - g[i], fr, g[i]);
        const float uv = (fv - hv) / gv;
        lq[j] = fmaf(0.5f * uv * uv, dtv, lq[j]);
        const float ynew = fmaf(fv, dtv, yt) + gv * sqdt * sN[cur][row][col];
        sY32[cur ^ 1][row][col] = ynew;
        sY16[cur ^ 1][row][col] = (h1)ynew;
      }
    } else if (w < 4) {
      f32x4 ap{0, 0, 0, 0};
      ap = MFMA(afrag(&sY16[cur][0][0], 40, 0, lane), wPj, ap);
      const int cc = 16 * (w - 2) + coln;
#pragma unroll
      for (int j = 0; j < 4; ++j)
        out[((size_t)t * BB + b0 + row4 + j) * DD + cc] = ap[j] + bPj;
    }
    __syncthreads();  // BAR3
  }

  // final projection xs_hat[99]
  if (w >= 2 && w < 4) {
    f32x4 ap{0, 0, 0, 0};
    ap = MFMA(afrag(&sY16[(TT - 1) & 1][0][0], 40, 0, lane), wPj, ap);
    const int cc = 16 * (w - 2) + coln;
#pragma unroll
    for (int j = 0; j < 4; ++j)
      out[((size_t)(TT - 1) * BB + b0 + row4 + j) * DD + cc] = ap[j] + bPj;
  }
  if (w < 2) {
#pragma unroll
    for (int j = 0; j < 4; ++j) sLq[row4 + j][16 * w + coln] = lq[j];
  }
  __syncthreads();
  if (tid < 16) {
    float s = 0.f;
#pragma unroll
    for (int k = 0; k < 32; ++k) s += sLq[tid][k];
    out[(size_t)TT * BB * DD + b0 + tid] = s;
  }
}

extern "C" void kernel_launch(void* const* d_in, const int* in_sizes, int n_in,
                              void* d_out, int out_size, void* d_ws,
                              size_t ws_size, hipStream_t stream) {
  const float* xs = (const float*)d_in[0];
  const float* ts = (const float*)d_in[1];
  const float* eps0 = (const float*)d_in[2];
  const float* noise = (const float*)d_in[3];
  const float* Wih = (const float*)d_in[4];
  const float* Whh = (const float*)d_in[5];
  const float* bih = (const float*)d_in[6];
  const float* bhh = (const float*)d_in[7];
  const float* encW = (const float*)d_in[8];
  const float* encb = (const float*)d_in[9];
  const float* qz0W = (const float*)d_in[10];
  const float* qz0b = (const float*)d_in[11];
  const float* fW1 = (const float*)d_in[12];
  const float* fb1 = (const float*)d_in[13];
  const float* fW2 = (const float*)d_in[14];
  const float* fb2 = (const float*)d_in[15];
  const float* fW3 = (const float*)d_in[16];
  const float* fb3 = (const float*)d_in[17];
  const float* hW1 = (const float*)d_in[18];
  const float* hb1 = (const float*)d_in[19];
  const float* hW2 = (const float*)d_in[20];
  const float* hb2 = (const float*)d_in[21];
  const float* hW3 = (const float*)d_in[22];
  const float* hb3 = (const float*)d_in[23];
  const float* gW1 = (const float*)d_in[24];
  const float* gb1 = (const float*)d_in[25];
  const float* gW2 = (const float*)d_in[26];
  const float* gb2 = (const float*)d_in[27];
  const float* projW = (const float*)d_in[28];
  const float* projb = (const float*)d_in[29];
  float* out = (float*)d_out;
  h1* ctx16 = (h1*)d_out;      // ctx[t,b,64] f16 aliases xs_hat[t,b,32] f32
  float* gtab = (float*)d_ws;  // 32*260*4 B

  k_gtab<<<32, 320, 0, stream>>>(gW1, gb1, gW2, gb2, gtab);
  k_gru<<<256, 1024, 0, stream>>>(xs, Wih, Whh, bih, bhh, encW, encb, ctx16);
  k_sde<<<256, 1024, 0, stream>>>(ts, eps0, noise, qz0W, qz0b, fW1, fb1, fW2,
                                  fb2, fW3, fb3, hW1, hb1, hW2, hb2, hW3, hb3,
                                  projW, projb, gtab, ctx16, out);
}

// Round 7
// 393.163 us; speedup vs baseline: 1.7590x; 1.1805x over previous
//
#include <hip/hip_runtime.h>

// RallyNet latent-SDE, round 7.
// Round-4 structure (256 blocks x 512 threads, 16 rows/block, VGPR-safe)
// + raw barriers (lgkmcnt-only, vmcnt never drained at barriers -> global
//   prefetches/stores stay in flight across phases),
// + in-register Euler-Maruyama on waves 0-1 (y in registers, noise direct
//   to registers, g-gather on 2 waves only), projection on waves 2-3,
// + fW3/hW3/encW in XOR-swizzled LDS (conflict-free B-frag reads) to keep
//   pinned-register count at 12 frags/wave (no rematerialization).
// ctx[t,b,:] f16 aliases xs_hat[t,b,:] f32 inside d_out.

#define TT 100
#define BB 4096
#define DD 32
#define LL 32
#define CC 64
#define HH 128
#define GROW 260

typedef _Float16 h1;
typedef _Float16 h2 __attribute__((ext_vector_type(2)));
typedef _Float16 f16x8 __attribute__((ext_vector_type(8)));
typedef float f32x4 __attribute__((ext_vector_type(4)));

#define MFMA(a, b, c) __builtin_amdgcn_mfma_f32_16x16x32_f16(a, b, c, 0, 0, 0)
#define PIN(x) asm volatile("" : "+v"(x))

// Barrier that drains ONLY LDS ops (producer->consumer), never vmcnt:
// global loads to registers are per-wave private; stores need no cross-wave
// visibility inside the kernel. Keeps prefetches in flight across phases.
__device__ __forceinline__ void bar_lds() {
  __builtin_amdgcn_sched_barrier(0);
  asm volatile("s_waitcnt lgkmcnt(0)" ::: "memory");
  __builtin_amdgcn_s_barrier();
  asm volatile("" ::: "memory");
  __builtin_amdgcn_sched_barrier(0);
}

__device__ __forceinline__ float sigm(float x) {
  return 1.0f / (1.0f + __expf(-x));
}
__device__ __forceinline__ float tanh_(float x) {
  float xc = fminf(fmaxf(x, -15.0f), 15.0f);
  float e = __expf(2.0f * xc);
  return (e - 1.0f) / (e + 1.0f);
}
__device__ __forceinline__ float splus(float x) {
  float t = __logf(1.0f + __expf(fminf(x, 15.0f)));
  return x > 15.0f ? x : t;
}

// B-fragment of row-major W[N][K] tile (n0,k0): lane l reg j ->
// B[k0+(l>>4)*8+j][n0+(l&15)]
__device__ __forceinline__ f16x8 bfrag(const float* __restrict__ W, int K,
                                       int n0, int k0, int lane) {
  const float* p = W + (size_t)(n0 + (lane & 15)) * K + k0 + ((lane >> 4) << 3);
  f16x8 r;
#pragma unroll
  for (int j = 0; j < 8; ++j) r[j] = (h1)p[j];
  return r;
}

// A-fragment from LDS row-major tile (ld f16/row, rows 16B-aligned)
__device__ __forceinline__ f16x8 afrag(const h1* base, int ld, int k0,
                                       int lane) {
  return *(const f16x8*)(base + (size_t)(lane & 15) * ld + k0 +
                         ((lane >> 4) << 3));
}

// ---- swizzled f16 weight LDS (rows of 128 f16 = 256B; XOR bits 4-6 by row)
__device__ __forceinline__ void store_swz(h1* base, const float* __restrict__ W,
                                          int rows, int tid, int nthr) {
  for (int idx = tid; idx < rows * 64; idx += nthr) {
    const int n = idx >> 6, kp = idx & 63;  // k = 2*kp
    float2 v = *(const float2*)(W + (size_t)n * HH + 2 * kp);
    h2 hv;
    hv[0] = (h1)v.x;
    hv[1] = (h1)v.y;
    int byte = n * 256 + kp * 4;
    byte ^= (n & 7) << 4;
    *(h2*)((char*)base + byte) = hv;
  }
}
__device__ __forceinline__ f16x8 swzfrag(const h1* base, int n0, int kt,
                                         int lane) {
  const int n = n0 + (lane & 15);
  int byte = n * 256 + kt * 64 + ((lane >> 4) << 4);
  byte ^= (n & 7) << 4;
  return *(const f16x8*)((const char*)base + byte);
}

// ---------------- g-table build: 32 blocks x 320 threads ----------------
__global__ __launch_bounds__(320) void k_gtab(
    const float* __restrict__ gW1, const float* __restrict__ gb1,
    const float* __restrict__ gW2, const float* __restrict__ gb2,
    float* __restrict__ gtab) {
  const int l = blockIdx.x;
  const int e = threadIdx.x;
  if (e >= 257) return;
  const float yv = -12.f + (float)e * (24.f / 256.f);
  const float* w1 = gW1 + l * HH;
  const float* bb = gb1 + l * HH;
  const float* w2 = gW2 + l * HH;
  float a = 0.f;
#pragma unroll 4
  for (int h = 0; h < HH; ++h)
    a = fmaf(splus(fmaf(yv, w1[h], bb[h])), w2[h], a);
  gtab[l * GROW + e] = sigm(a + gb2[l]);
}

// ---------------- Kernel 1: GRU + encoder, 1 raw barrier/step ----------------
__global__ __launch_bounds__(512, 2) void k_gru(
    const float* __restrict__ xs, const float* __restrict__ Wih,
    const float* __restrict__ Whh, const float* __restrict__ bih,
    const float* __restrict__ bhh, const float* __restrict__ encW,
    const float* __restrict__ encb, h1* __restrict__ ctx16) {
  __shared__ alignas(16) h1 sH[2][16][136];
  __shared__ alignas(16) h1 sX[2][16][40];
  __shared__ alignas(16) h1 sE[64 * 128];  // swizzled encW

  const int tid = threadIdx.x;
  const int lane = tid & 63, w = tid >> 6;
  const int b0 = blockIdx.x * 16;
  const int coln = lane & 15, row4 = (lane >> 4) << 2;

  f16x8 wIH[3], wHH[3][4];
#pragma unroll
  for (int g = 0; g < 3; ++g) {
    wIH[g] = bfrag(Wih, DD, 128 * g + 16 * w, 0, lane);
#pragma unroll
    for (int kt = 0; kt < 4; ++kt)
      wHH[g][kt] = bfrag(Whh, HH, 128 * g + 16 * w, 32 * kt, lane);
  }
  const int m = 16 * w + coln;
  const float b_r = bih[m] + bhh[m];
  const float b_z = bih[128 + m] + bhh[128 + m];
  const float b_ni = bih[256 + m];
  const float b_nh = bhh[256 + m];
  const int ccE = (w >= 4) ? 16 * (w - 4) + coln : 0;
  const float bE = (w >= 4) ? encb[ccE] : 0.f;

  store_swz(sE, encW, 64, tid, 512);
  for (int i = tid; i < 16 * 136; i += 512) (&sH[0][0][0])[i] = (h1)0.0f;
  sX[0][tid >> 5][tid & 31] = (h1)xs[(size_t)b0 * DD + tid];
  float xHold = xs[(size_t)1 * BB * DD + (size_t)b0 * DD + tid];
  float hold[4] = {0.f, 0.f, 0.f, 0.f};
  __syncthreads();

  for (int t = 0; t < TT; ++t) {
    const int cur = t & 1;
    const int tf = (t + 2 < TT) ? (t + 2) : (TT - 1);
    const float xFly = xs[(size_t)tf * BB * DD + (size_t)b0 * DD + tid];

#pragma unroll
    for (int g = 0; g < 3; ++g) {
      PIN(wIH[g]);
#pragma unroll
      for (int kt = 0; kt < 4; ++kt) PIN(wHH[g][kt]);
    }

    f16x8 ax = afrag(&sX[cur][0][0], 40, 0, lane);
    f32x4 aR{0, 0, 0, 0}, aZ{0, 0, 0, 0}, aNI{0, 0, 0, 0}, aNH{0, 0, 0, 0};
    aR = MFMA(ax, wIH[0], aR);
    aZ = MFMA(ax, wIH[1], aZ);
    aNI = MFMA(ax, wIH[2], aNI);
#pragma unroll
    for (int kt = 0; kt < 4; ++kt) {
      f16x8 ah = afrag(&sH[cur][0][0], 136, 32 * kt, lane);
      aR = MFMA(ah, wHH[0][kt], aR);
      aZ = MFMA(ah, wHH[1][kt], aZ);
      aNH = MFMA(ah, wHH[2][kt], aNH);
    }
#pragma unroll
    for (int j = 0; j < 4; ++j) {
      float rg = sigm(aR[j] + b_r);
      float zg = sigm(aZ[j] + b_z);
      float ng = tanh_(aNI[j] + b_ni + rg * (aNH[j] + b_nh));
      float hn = (1.0f - zg) * ng + zg * hold[j];
      hold[j] = hn;
      sH[cur ^ 1][row4 + j][m] = (h1)hn;
    }
    sX[cur ^ 1][tid >> 5][tid & 31] = (h1)xHold;
    bar_lds();  // the only barrier per step (lgkm-only)

    // encoder from updated h; B-frags from swizzled LDS; 2B stores fly free
    if (w >= 4) {
      f32x4 aE{0, 0, 0, 0};
#pragma unroll
      for (int kt = 0; kt < 4; ++kt)
        aE = MFMA(afrag(&sH[cur ^ 1][0][0], 136, 32 * kt, lane),
                  swzfrag(sE, 16 * (w - 4), kt, lane), aE);
#pragma unroll
      for (int j = 0; j < 4; ++j)
        ctx16[((size_t)t * BB + b0 + row4 + j) * CC + ccE] = (h1)(aE[j] + bE);
    }
    xHold = xFly;
  }
}

// ---------------- Kernel 2: z0 + SDE scan + projection ----------------
__global__ __launch_bounds__(512, 2) void k_sde(
    const float* __restrict__ ts, const float* __restrict__ eps0,
    const float* __restrict__ noise, const float* __restrict__ qz0W,
    const float* __restrict__ qz0b, const float* __restrict__ fW1,
    const float* __restrict__ fb1, const float* __restrict__ fW2,
    const float* __restrict__ fb2, const float* __restrict__ fW3,
    const float* __restrict__ fb3, const float* __restrict__ hW1,
    const float* __restrict__ hb1, const float* __restrict__ hW2,
    const float* __restrict__ hb2, const float* __restrict__ hW3,
    const float* __restrict__ hb3, const float* __restrict__ projW,
    const float* __restrict__ projb, const float* __restrict__ gtab,
    const h1* __restrict__ ctx16, float* __restrict__ out) {
  __shared__ alignas(16) h1 sC[2][16][72];
  __shared__ alignas(16) h1 sY16[2][16][40];
  __shared__ alignas(16) h1 sA1[16][136], sB1[16][136];
  __shared__ alignas(16) h1 sA2[16][136], sB2[16][136];
  __shared__ alignas(16) h1 sW3f[32 * 128], sW3h[32 * 128];  // swizzled
  __shared__ float sG[32][GROW];
  __shared__ float sDt[128], sSq[128];
  __shared__ float sTmp[16][33];  // z0 staging, later logqp staging

  const int tid = threadIdx.x;
  const int lane = tid & 63, w = tid >> 6;
  const int b0 = blockIdx.x * 16;
  const int coln = lane & 15, row4 = (lane >> 4) << 2;
  const int sr = tid >> 5, sc = tid & 31;
  const int cc = 16 * w + coln;

  // every-phase weights pinned (12 frags = 48 VGPR); layer-3 in swz LDS
  f16x8 wF1[3], wH1v, wF2[4], wH2[4], wPj;
#pragma unroll
  for (int kt = 0; kt < 3; ++kt)
    wF1[kt] = bfrag(fW1, 96, 16 * w, 32 * kt, lane);
  wH1v = bfrag(hW1, 32, 16 * w, 0, lane);
#pragma unroll
  for (int kt = 0; kt < 4; ++kt) {
    wF2[kt] = bfrag(fW2, HH, 16 * w, 32 * kt, lane);
    wH2[kt] = bfrag(hW2, HH, 16 * w, 32 * kt, lane);
  }
  const float bF1 = fb1[cc], bH1 = hb1[cc], bF2 = fb2[cc], bH2 = hb2[cc];
  float bF3 = 0.f, bH3 = 0.f, bPj = 0.f;
  int ccp = 0;
  if (w < 2) {
    bF3 = fb3[cc];
    bH3 = hb3[cc];
  } else if (w < 4) {
    ccp = 16 * (w - 2) + coln;
    wPj = bfrag(projW, LL, 16 * (w - 2), 0, lane);
    bPj = projb[ccp];
  }

  store_swz(sW3f, fW3, 32, tid, 512);
  store_swz(sW3h, hW3, 32, tid, 512);
  for (int i = tid; i < 32 * GROW; i += 512) (&sG[0][0])[i] = gtab[i];
  if (tid < TT - 1) {
    float d = ts[tid + 1] - ts[tid];
    sDt[tid] = d;
    sSq[tid] = __fsqrt_rn(d);
  }
  *(h2*)&sC[0][sr][2 * sc] =
      *(const h2*)(ctx16 + (size_t)(b0 + sr) * CC + 2 * sc);
  __syncthreads();

  // z0 = mean + exp(logstd)*eps0
  {
    float m0 = qz0b[sc], s0 = qz0b[32 + sc];
    const float* qm = qz0W + sc * 64;
    const float* qs = qz0W + (32 + sc) * 64;
#pragma unroll 4
    for (int k = 0; k < 64; ++k) {
      float cv = (float)sC[0][sr][k];
      m0 = fmaf(qm[k], cv, m0);
      s0 = fmaf(qs[k], cv, s0);
    }
    float z = fmaf(__expf(s0), eps0[(size_t)(b0 + sr) * LL + sc], m0);
    sTmp[sr][sc] = z;
    sY16[0][sr][sc] = (h1)z;
  }
  __syncthreads();

  // y lives in w0-1 registers: lane owns (rows row4..row4+3, col cc)
  float yreg[4] = {0.f, 0.f, 0.f, 0.f}, lq[4] = {0.f, 0.f, 0.f, 0.f};
  if (w < 2) {
#pragma unroll
    for (int j = 0; j < 4; ++j) yreg[j] = sTmp[row4 + j][cc];
  }

  for (int t = 0; t < TT - 1; ++t) {
    const int cur = t & 1;
    // prefetches: stay in flight across raw barriers (no vmcnt drain)
    const h2 cpre =
        *(const h2*)(ctx16 + ((size_t)(t + 1) * BB + b0 + sr) * CC + 2 * sc);
    float nv[4] = {0.f, 0.f, 0.f, 0.f};
    if (w < 2) {
#pragma unroll
      for (int j = 0; j < 4; ++j)
        nv[j] = noise[((size_t)t * BB + b0 + row4 + j) * LL + cc];
    }

#pragma unroll
    for (int kt = 0; kt < 3; ++kt) PIN(wF1[kt]);
    PIN(wH1v);
#pragma unroll
    for (int kt = 0; kt < 4; ++kt) {
      PIN(wF2[kt]);
      PIN(wH2[kt]);
    }
    if (w >= 2 && w < 4) PIN(wPj);

    // ---- P1: a1 = sp(fW1*[y;c]+b), b1 = sp(hW1*y+b) ----
    f16x8 aY = afrag(&sY16[cur][0][0], 40, 0, lane);
    {
      f16x8 aC0 = afrag(&sC[cur][0][0], 72, 0, lane);
      f16x8 aC1 = afrag(&sC[cur][0][0], 72, 32, lane);
      f32x4 aF{0, 0, 0, 0}, aH{0, 0, 0, 0};
      aF = MFMA(aY, wF1[0], aF);
      aF = MFMA(aC0, wF1[1], aF);
      aF = MFMA(aC1, wF1[2], aF);
      aH = MFMA(aY, wH1v, aH);
#pragma unroll
      for (int j = 0; j < 4; ++j) {
        sA1[row4 + j][cc] = (h1)splus(aF[j] + bF1);
        sB1[row4 + j][cc] = (h1)splus(aH[j] + bH1);
      }
    }
    bar_lds();  // BAR1

    // ---- P2: a2/b2; stage prefetched ctx ----
    {
      f32x4 aF{0, 0, 0, 0}, aH{0, 0, 0, 0};
#pragma unroll
      for (int kt = 0; kt < 4; ++kt) {
        aF = MFMA(afrag(&sA1[0][0], 136, 32 * kt, lane), wF2[kt], aF);
        aH = MFMA(afrag(&sB1[0][0], 136, 32 * kt, lane), wH2[kt], aH);
      }
#pragma unroll
      for (int j = 0; j < 4; ++j) {
        sA2[row4 + j][cc] = (h1)splus(aF[j] + bF2);
        sB2[row4 + j][cc] = (h1)splus(aH[j] + bH2);
      }
    }
    *(h2*)&sC[cur ^ 1][sr][2 * sc] = cpre;
    bar_lds();  // BAR2

    // ---- P3: w0-1 f3+h3+in-register update; w2-3 projection of zs[t] ----
    if (w < 2) {
      f32x4 aF{0, 0, 0, 0}, aH{0, 0, 0, 0};
#pragma unroll
      for (int kt = 0; kt < 4; ++kt) {
        aF = MFMA(afrag(&sA2[0][0], 136, 32 * kt, lane),
                  swzfrag(sW3f, 16 * w, kt, lane), aF);
        aH = MFMA(afrag(&sB2[0][0], 136, 32 * kt, lane),
                  swzfrag(sW3h, 16 * w, kt, lane), aH);
      }
      const float dtv = sDt[t], sqdt = sSq[t];
      const float* g = sG[cc];
#pragma unroll
      for (int j = 0; j < 4; ++j) {
        const float fv = aF[j] + bF3;
        const float hv = aH[j] + bH3;
        float p = fminf(fmaxf(fmaf(yreg[j], 32.f / 3.f, 128.f), 0.f), 255.999f);
        const int i = (int)p;
        const float fr = p - (float)i;
        const float gv = fmaf(g[i + 1] - g[i], fr, g[i]);
        const float uv = (fv - hv) / gv;
        lq[j] = fmaf(0.5f * uv * uv, dtv, lq[j]);
        yreg[j] = fmaf(fv, dtv, yreg[j]) + gv * sqdt * nv[j];
        sY16[cur ^ 1][row4 + j][cc] = (h1)yreg[j];
      }
    } else if (w < 4) {
      f32x4 ap{0, 0, 0, 0};
      ap = MFMA(aY, wPj, ap);
#pragma unroll
      for (int j = 0; j < 4; ++j)
        out[((size_t)t * BB + b0 + row4 + j) * DD + ccp] = ap[j] + bPj;
    }
    bar_lds();  // BAR3
  }

  // final projection xs_hat[99]
  if (w >= 2 && w < 4) {
    f16x8 aYf = afrag(&sY16[(TT - 1) & 1][0][0], 40, 0, lane);
    f32x4 ap{0, 0, 0, 0};
    ap = MFMA(aYf, wPj, ap);
#pragma unroll
    for (int j = 0; j < 4; ++j)
      out[((size_t)(TT - 1) * BB + b0 + row4 + j) * DD + ccp] = ap[j] + bPj;
  }
  // logqp: per-row col-sum via sTmp
  if (w < 2) {
#pragma unroll
    for (int j = 0; j < 4; ++j) sTmp[row4 + j][cc] = lq[j];
  }
  __syncthreads();
  if (tid < 16) {
    float s = 0.f;
#pragma unroll
    for (int k = 0; k < 32; ++k) s += sTmp[tid][k];
    out[(size_t)TT * BB * DD + b0 + tid] = s;
  }
}

extern "C" void kernel_launch(void* const* d_in, const int* in_sizes, int n_in,
                              void* d_out, int out_size, void* d_ws,
                              size_t ws_size, hipStream_t stream) {
  const float* xs = (const float*)d_in[0];
  const float* ts = (const float*)d_in[1];
  const float* eps0 = (const float*)d_in[2];
  const float* noise = (const float*)d_in[3];
  const float* Wih = (const float*)d_in[4];
  const float* Whh = (const float*)d_in[5];
  const float* bih = (const float*)d_in[6];
  const float* bhh = (const float*)d_in[7];
  const float* encW = (const float*)d_in[8];
  const float* encb = (const float*)d_in[9];
  const float* qz0W = (const float*)d_in[10];
  const float* qz0b = (const float*)d_in[11];
  const float* fW1 = (const float*)d_in[12];
  const float* fb1 = (const float*)d_in[13];
  const float* fW2 = (const float*)d_in[14];
  const float* fb2 = (const float*)d_in[15];
  const float* fW3 = (const float*)d_in[16];
  const float* fb3 = (const float*)d_in[17];
  const float* hW1 = (const float*)d_in[18];
  const float* hb1 = (const float*)d_in[19];
  const float* hW2 = (const float*)d_in[20];
  const float* hb2 = (const float*)d_in[21];
  const float* hW3 = (const float*)d_in[22];
  const float* hb3 = (const float*)d_in[23];
  const float* gW1 = (const float*)d_in[24];
  const float* gb1 = (const float*)d_in[25];
  const float* gW2 = (const float*)d_in[26];
  const float* gb2 = (const float*)d_in[27];
  const float* projW = (const float*)d_in[28];
  const float* projb = (const float*)d_in[29];
  float* out = (float*)d_out;
  h1* ctx16 = (h1*)d_out;      // ctx[t,b,64] f16 aliases xs_hat[t,b,32] f32
  float* gtab = (float*)d_ws;  // 32*260*4 B

  k_gtab<<<32, 320, 0, stream>>>(gW1, gb1, gW2, gb2, gtab);
  k_gru<<<256, 512, 0, stream>>>(xs, Wih, Whh, bih, bhh, encW, encb, ctx16);
  k_sde<<<256, 512, 0, stream>>>(ts, eps0, noise, qz0W, qz0b, fW1, fb1, fW2,
                                 fb2, fW3, fb3, hW1, hb1, hW2, hb2, hW3, hb3,
                                 projW, projb, gtab, ctx16, out);
}

// Round 8
// 375.690 us; speedup vs baseline: 1.8409x; 1.0465x over previous
//
#include <hip/hip_runtime.h>

// RallyNet latent-SDE, round 8.
// 256 blocks x 1024 threads (16 waves, 4/SIMD via amdgpu_waves_per_eu(4,4)),
// 16 batch rows/block. Wave specialization with register-pinned weights:
//  k_sde: w0-7 f-path, w8-15 h-path + ctx staging; P3: w8-9 f3+h3 (swizzled
//         LDS weights) + in-register Euler-Maruyama, w10-11 projection.
//         3 lgkm-only barriers/step (global prefetches never drained).
//  k_gru: w0-7 gates || w8-11 encoder(t-1) || w12-15 x staging, 1 barrier.
// diag-g via PWL table (d_ws). ctx[t,b,:] f16 aliases xs_hat[t,b,:] f32.

#define TT 100
#define BB 4096
#define DD 32
#define LL 32
#define CC 64
#define HH 128
#define GROW 260

typedef _Float16 h1;
typedef _Float16 h2 __attribute__((ext_vector_type(2)));
typedef _Float16 f16x8 __attribute__((ext_vector_type(8)));
typedef float f32x4 __attribute__((ext_vector_type(4)));

#define MFMA(a, b, c) __builtin_amdgcn_mfma_f32_16x16x32_f16(a, b, c, 0, 0, 0)
#define PIN(x) asm volatile("" : "+v"(x))

// lgkmcnt-only barrier: LDS producer->consumer ordering without draining
// vmcnt (global prefetches/stores stay in flight across phases).
__device__ __forceinline__ void bar_lds() {
  __builtin_amdgcn_sched_barrier(0);
  asm volatile("s_waitcnt lgkmcnt(0)" ::: "memory");
  __builtin_amdgcn_s_barrier();
  asm volatile("" ::: "memory");
  __builtin_amdgcn_sched_barrier(0);
}

__device__ __forceinline__ float sigm(float x) {
  return 1.0f / (1.0f + __expf(-x));
}
__device__ __forceinline__ float tanh_(float x) {
  float e = __expf(2.0f * fminf(x, 15.0f));
  return (e - 1.0f) / (e + 1.0f);
}
__device__ __forceinline__ float splus(float x) {
  return __logf(1.0f + __expf(x));  // inputs bounded |x| << 80
}

// B-fragment of row-major W[N][K] tile (n0,k0)
__device__ __forceinline__ f16x8 bfrag(const float* __restrict__ W, int K,
                                       int n0, int k0, int lane) {
  const float* p = W + (size_t)(n0 + (lane & 15)) * K + k0 + ((lane >> 4) << 3);
  f16x8 r;
#pragma unroll
  for (int j = 0; j < 8; ++j) r[j] = (h1)p[j];
  return r;
}

// A-fragment from LDS row-major tile
__device__ __forceinline__ f16x8 afrag(const h1* base, int ld, int k0,
                                       int lane) {
  return *(const f16x8*)(base + (size_t)(lane & 15) * ld + k0 +
                         ((lane >> 4) << 3));
}

// swizzled f16 weight LDS (rows 256B; XOR bits 4-6 by row&7)
__device__ __forceinline__ void store_swz(h1* base, const float* __restrict__ W,
                                          int rows, int tid, int nthr) {
  for (int idx = tid; idx < rows * 64; idx += nthr) {
    const int n = idx >> 6, kp = idx & 63;
    float2 v = *(const float2*)(W + (size_t)n * HH + 2 * kp);
    h2 hv;
    hv[0] = (h1)v.x;
    hv[1] = (h1)v.y;
    int byte = n * 256 + kp * 4;
    byte ^= (n & 7) << 4;
    *(h2*)((char*)base + byte) = hv;
  }
}
__device__ __forceinline__ f16x8 swzfrag(const h1* base, int n0, int kt,
                                         int lane) {
  const int n = n0 + (lane & 15);
  int byte = n * 256 + kt * 64 + ((lane >> 4) << 4);
  byte ^= (n & 7) << 4;
  return *(const f16x8*)((const char*)base + byte);
}

// ---------------- g-table build ----------------
__global__ __launch_bounds__(320) void k_gtab(
    const float* __restrict__ gW1, const float* __restrict__ gb1,
    const float* __restrict__ gW2, const float* __restrict__ gb2,
    float* __restrict__ gtab) {
  const int l = blockIdx.x;
  const int e = threadIdx.x;
  if (e >= 257) return;
  const float yv = -12.f + (float)e * (24.f / 256.f);
  const float* w1 = gW1 + l * HH;
  const float* bb = gb1 + l * HH;
  const float* w2 = gW2 + l * HH;
  float a = 0.f;
#pragma unroll 4
  for (int h = 0; h < HH; ++h)
    a = fmaf(splus(fmaf(yv, w1[h], bb[h])), w2[h], a);
  gtab[l * GROW + e] = sigm(a + gb2[l]);
}

// ---------------- Kernel 1: GRU + encoder ----------------
__global__ __attribute__((amdgpu_flat_work_group_size(1024, 1024),
                          amdgpu_waves_per_eu(4, 4))) void k_gru(
    const float* __restrict__ xs, const float* __restrict__ Wih,
    const float* __restrict__ Whh, const float* __restrict__ bih,
    const float* __restrict__ bhh, const float* __restrict__ encW,
    const float* __restrict__ encb, h1* __restrict__ ctx16) {
  __shared__ alignas(16) h1 sH[2][16][136];
  __shared__ alignas(16) h1 sX[2][16][40];

  const int tid = threadIdx.x;
  const int lane = tid & 63, w = tid >> 6;
  const int b0 = blockIdx.x * 16;
  const int coln = lane & 15, row4 = (lane >> 4) << 2;
  const int sidx = tid - 768;  // waves 12-15 -> 0..255

  f16x8 wIH[3], wHH[3][4], wE[4];
  float b_r = 0, b_z = 0, b_ni = 0, b_nh = 0, bE = 0;
  int m = 0, ccE = 0;
  if (w < 8) {
    m = 16 * w + coln;
#pragma unroll
    for (int g = 0; g < 3; ++g) {
      wIH[g] = bfrag(Wih, DD, 128 * g + 16 * w, 0, lane);
#pragma unroll
      for (int kt = 0; kt < 4; ++kt)
        wHH[g][kt] = bfrag(Whh, HH, 128 * g + 16 * w, 32 * kt, lane);
    }
    b_r = bih[m] + bhh[m];
    b_z = bih[128 + m] + bhh[128 + m];
    b_ni = bih[256 + m];
    b_nh = bhh[256 + m];
  } else if (w < 12) {
    ccE = 16 * (w - 8) + coln;
#pragma unroll
    for (int kt = 0; kt < 4; ++kt)
      wE[kt] = bfrag(encW, HH, 16 * (w - 8), 32 * kt, lane);
    bE = encb[ccE];
  }

  for (int i = tid; i < 16 * 136; i += 1024) (&sH[0][0][0])[i] = (h1)0.0f;
  float2 xHold = {0.f, 0.f};
  if (sidx >= 0 && sidx < 256) {
    const int xr = sidx >> 4, xp = sidx & 15;
    float2 v = *(const float2*)(xs + (size_t)(b0 + xr) * DD + 2 * xp);
    h2 hv;
    hv[0] = (h1)v.x;
    hv[1] = (h1)v.y;
    *(h2*)&sX[0][xr][2 * xp] = hv;
    xHold = *(const float2*)(xs + ((size_t)BB + b0 + xr) * DD + 2 * xp);
  }
  float hold[4] = {0.f, 0.f, 0.f, 0.f};
  __syncthreads();

  // interval t: gates(t) w0-7 || enc(t-1) w8-11 || stage x(t+1) w12-15
  for (int t = 0; t <= TT; ++t) {
    const int buf = t & 1;
    if (w < 8) {
      if (t < TT) {
#pragma unroll
        for (int g = 0; g < 3; ++g) {
          PIN(wIH[g]);
#pragma unroll
          for (int kt = 0; kt < 4; ++kt) PIN(wHH[g][kt]);
        }
        f16x8 ax = afrag(&sX[buf][0][0], 40, 0, lane);
        f32x4 aR{b_r, b_r, b_r, b_r}, aZ{b_z, b_z, b_z, b_z};
        f32x4 aNI{b_ni, b_ni, b_ni, b_ni}, aNH{b_nh, b_nh, b_nh, b_nh};
        aR = MFMA(ax, wIH[0], aR);
        aZ = MFMA(ax, wIH[1], aZ);
        aNI = MFMA(ax, wIH[2], aNI);
#pragma unroll
        for (int kt = 0; kt < 4; ++kt) {
          f16x8 ah = afrag(&sH[buf][0][0], 136, 32 * kt, lane);
          aR = MFMA(ah, wHH[0][kt], aR);
          aZ = MFMA(ah, wHH[1][kt], aZ);
          aNH = MFMA(ah, wHH[2][kt], aNH);
        }
#pragma unroll
        for (int j = 0; j < 4; ++j) {
          float rg = sigm(aR[j]);
          float zg = sigm(aZ[j]);
          float ng = tanh_(aNI[j] + rg * aNH[j]);
          float hn = (1.0f - zg) * ng + zg * hold[j];
          hold[j] = hn;
          sH[buf ^ 1][row4 + j][m] = (h1)hn;
        }
      }
    } else if (w < 12) {
      if (t >= 1) {
#pragma unroll
        for (int kt = 0; kt < 4; ++kt) PIN(wE[kt]);
        f32x4 aE{bE, bE, bE, bE};
#pragma unroll
        for (int kt = 0; kt < 4; ++kt)
          aE = MFMA(afrag(&sH[buf][0][0], 136, 32 * kt, lane), wE[kt], aE);
#pragma unroll
        for (int j = 0; j < 4; ++j)
          ctx16[((size_t)(t - 1) * BB + b0 + row4 + j) * CC + ccE] = (h1)aE[j];
      }
    } else {
      if (sidx < 256 && t + 1 < TT) {
        const int xr = sidx >> 4, xp = sidx & 15;
        h2 hv;
        hv[0] = (h1)xHold.x;
        hv[1] = (h1)xHold.y;
        *(h2*)&sX[buf ^ 1][xr][2 * xp] = hv;
        const int tf = (t + 2 < TT) ? (t + 2) : (TT - 1);
        xHold = *(const float2*)(xs + ((size_t)tf * BB + b0 + xr) * DD + 2 * xp);
      }
    }
    bar_lds();
  }
}

// ---------------- Kernel 2: z0 + SDE scan + projection ----------------
__global__ __attribute__((amdgpu_flat_work_group_size(1024, 1024),
                          amdgpu_waves_per_eu(4, 4))) void k_sde(
    const float* __restrict__ ts, const float* __restrict__ eps0,
    const float* __restrict__ noise, const float* __restrict__ qz0W,
    const float* __restrict__ qz0b, const float* __restrict__ fW1,
    const float* __restrict__ fb1, const float* __restrict__ fW2,
    const float* __restrict__ fb2, const float* __restrict__ fW3,
    const float* __restrict__ fb3, const float* __restrict__ hW1,
    const float* __restrict__ hb1, const float* __restrict__ hW2,
    const float* __restrict__ hb2, const float* __restrict__ hW3,
    const float* __restrict__ hb3, const float* __restrict__ projW,
    const float* __restrict__ projb, const float* __restrict__ gtab,
    const h1* __restrict__ ctx16, float* __restrict__ out) {
  __shared__ alignas(16) h1 sC[2][16][72];
  __shared__ alignas(16) h1 sY16[2][16][40];
  __shared__ alignas(16) h1 sA1[16][136], sB1[16][136];
  __shared__ alignas(16) h1 sA2[16][136], sB2[16][136];
  __shared__ alignas(16) h1 sW3f[32 * 128], sW3h[32 * 128];
  __shared__ float sG[32][GROW];
  __shared__ float sDt[128], sSq[128];
  __shared__ float sTmp[16][33];

  const int tid = threadIdx.x;
  const int lane = tid & 63, w = tid >> 6;
  const int b0 = blockIdx.x * 16;
  const int coln = lane & 15, row4 = (lane >> 4) << 2;
  const int sidx = tid - 512;  // waves 8-15 -> 0..511 (staging map)
  const bool isF = (w < 8);
  const int wt = isF ? w : w - 8;  // tile 0..7
  const int cc = 16 * wt + coln;

  // per-path pinned weights
  f16x8 wL1[3], wL2[4], wPj;
  if (isF) {
#pragma unroll
    for (int kt = 0; kt < 3; ++kt)
      wL1[kt] = bfrag(fW1, 96, 16 * wt, 32 * kt, lane);
#pragma unroll
    for (int kt = 0; kt < 4; ++kt)
      wL2[kt] = bfrag(fW2, HH, 16 * wt, 32 * kt, lane);
  } else {
    wL1[0] = bfrag(hW1, 32, 16 * wt, 0, lane);
#pragma unroll
    for (int kt = 0; kt < 4; ++kt)
      wL2[kt] = bfrag(hW2, HH, 16 * wt, 32 * kt, lane);
  }
  const float bL1 = isF ? fb1[cc] : hb1[cc];
  const float bL2 = isF ? fb2[cc] : hb2[cc];
  // update waves 8-9; projection waves 10-11
  float bF3 = 0.f, bH3 = 0.f, bPj = 0.f;
  int cu = 0, ccp = 0;
  if (w == 8 || w == 9) {
    cu = 16 * (w - 8) + coln;
    bF3 = fb3[cu];
    bH3 = hb3[cu];
  } else if (w == 10 || w == 11) {
    ccp = 16 * (w - 10) + coln;
    wPj = bfrag(projW, LL, 16 * (w - 10), 0, lane);
    bPj = projb[ccp];
  }

  store_swz(sW3f, fW3, 32, tid, 1024);
  store_swz(sW3h, hW3, 32, tid, 1024);
  for (int i = tid; i < 32 * GROW; i += 1024) (&sG[0][0])[i] = gtab[i];
  if (tid < TT - 1) {
    float d = ts[tid + 1] - ts[tid];
    sDt[tid] = d;
    sSq[tid] = __fsqrt_rn(d);
  }
  if (sidx >= 0) {
    const int sr = sidx >> 5, sc = sidx & 31;
    *(h2*)&sC[0][sr][2 * sc] =
        *(const h2*)(ctx16 + (size_t)(b0 + sr) * CC + 2 * sc);
  }
  __syncthreads();

  // z0 = mean + exp(logstd)*eps0 (waves 0-7)
  if (tid < 512) {
    const int sr = tid >> 5, sc = tid & 31;
    float m0 = qz0b[sc], s0 = qz0b[32 + sc];
    const float* qm = qz0W + sc * 64;
    const float* qs = qz0W + (32 + sc) * 64;
#pragma unroll 4
    for (int k = 0; k < 64; ++k) {
      float cv = (float)sC[0][sr][k];
      m0 = fmaf(qm[k], cv, m0);
      s0 = fmaf(qs[k], cv, s0);
    }
    float z = fmaf(__expf(s0), eps0[(size_t)(b0 + sr) * LL + sc], m0);
    sTmp[sr][sc] = z;
    sY16[0][sr][sc] = (h1)z;
  }
  __syncthreads();

  // y registers on waves 8-9: lane owns (rows row4..row4+3, col cu)
  float yreg[4] = {0.f, 0.f, 0.f, 0.f}, lq[4] = {0.f, 0.f, 0.f, 0.f};
  if (w == 8 || w == 9) {
#pragma unroll
    for (int j = 0; j < 4; ++j) yreg[j] = sTmp[row4 + j][cu];
  }

  for (int t = 0; t < TT - 1; ++t) {
    const int cur = t & 1;
    // prefetches (stay in flight across lgkm-only barriers)
    h2 cpre{(h1)0, (h1)0};
    if (sidx >= 0) {
      const int sr = sidx >> 5, sc = sidx & 31;
      cpre =
          *(const h2*)(ctx16 + ((size_t)(t + 1) * BB + b0 + sr) * CC + 2 * sc);
    }
    float nv[4] = {0.f, 0.f, 0.f, 0.f};
    if (w == 8 || w == 9) {
#pragma unroll
      for (int j = 0; j < 4; ++j)
        nv[j] = noise[((size_t)t * BB + b0 + row4 + j) * LL + cu];
    }

    if (isF) {
      PIN(wL1[0]);
      PIN(wL1[1]);
      PIN(wL1[2]);
    } else {
      PIN(wL1[0]);
    }
#pragma unroll
    for (int kt = 0; kt < 4; ++kt) PIN(wL2[kt]);
    if (w == 10 || w == 11) PIN(wPj);

    // ---- P1: layer 1 ----
    f16x8 aY = afrag(&sY16[cur][0][0], 40, 0, lane);
    if (isF) {
      f16x8 aC0 = afrag(&sC[cur][0][0], 72, 0, lane);
      f16x8 aC1 = afrag(&sC[cur][0][0], 72, 32, lane);
      f32x4 acc{bL1, bL1, bL1, bL1};
      acc = MFMA(aY, wL1[0], acc);
      acc = MFMA(aC0, wL1[1], acc);
      acc = MFMA(aC1, wL1[2], acc);
#pragma unroll
      for (int j = 0; j < 4; ++j) sA1[row4 + j][cc] = (h1)splus(acc[j]);
    } else {
      f32x4 acc{bL1, bL1, bL1, bL1};
      acc = MFMA(aY, wL1[0], acc);
#pragma unroll
      for (int j = 0; j < 4; ++j) sB1[row4 + j][cc] = (h1)splus(acc[j]);
    }
    bar_lds();  // BAR1

    // ---- P2: layer 2 (+ staging on h-waves) ----
    {
      const h1* src = isF ? &sA1[0][0] : &sB1[0][0];
      h1* dst = isF ? &sA2[0][0] : &sB2[0][0];
      f32x4 acc{bL2, bL2, bL2, bL2};
#pragma unroll
      for (int kt = 0; kt < 4; ++kt)
        acc = MFMA(afrag(src, 136, 32 * kt, lane), wL2[kt], acc);
#pragma unroll
      for (int j = 0; j < 4; ++j)
        dst[(size_t)(row4 + j) * 136 + cc] = (h1)splus(acc[j]);
    }
    if (sidx >= 0) {
      const int sr = sidx >> 5, sc = sidx & 31;
      *(h2*)&sC[cur ^ 1][sr][2 * sc] = cpre;
    }
    bar_lds();  // BAR2

    // ---- P3: w8-9 f3+h3+update; w10-11 projection of zs[t] ----
    if (w == 8 || w == 9) {
      f32x4 aF{bF3, bF3, bF3, bF3}, aH{bH3, bH3, bH3, bH3};
#pragma unroll
      for (int kt = 0; kt < 4; ++kt) {
        aF = MFMA(afrag(&sA2[0][0], 136, 32 * kt, lane),
                  swzfrag(sW3f, 16 * (w - 8), kt, lane), aF);
        aH = MFMA(afrag(&sB2[0][0], 136, 32 * kt, lane),
                  swzfrag(sW3h, 16 * (w - 8), kt, lane), aH);
      }
      const float dtv = sDt[t], sqdt = sSq[t];
      const float* g = sG[cu];
#pragma unroll
      for (int j = 0; j < 4; ++j) {
        float p = fminf(fmaxf(fmaf(yreg[j], 32.f / 3.f, 128.f), 0.f), 255.999f);
        const int i = (int)p;
        const float fr = p - (float)i;
        const float gv = fmaf(g[i + 1] - g[i], fr, g[i]);
        const float uv = (aF[j] - aH[j]) / gv;
        lq[j] = fmaf(0.5f * uv * uv, dtv, lq[j]);
        yreg[j] = fmaf(aF[j], dtv, yreg[j]) + gv * sqdt * nv[j];
        sY16[cur ^ 1][row4 + j][cu] = (h1)yreg[j];
      }
    } else if (w == 10 || w == 11) {
      f32x4 ap{bPj, bPj, bPj, bPj};
      ap = MFMA(aY, wPj, ap);
#pragma unroll
      for (int j = 0; j < 4; ++j)
        out[((size_t)t * BB + b0 + row4 + j) * DD + ccp] = ap[j];
    }
    bar_lds();  // BAR3
  }

  // final projection xs_hat[99]
  if (w == 10 || w == 11) {
    f16x8 aYf = afrag(&sY16[(TT - 1) & 1][0][0], 40, 0, lane);
    f32x4 ap{bPj, bPj, bPj, bPj};
    ap = MFMA(aYf, wPj, ap);
#pragma unroll
    for (int j = 0; j < 4; ++j)
      out[((size_t)(TT - 1) * BB + b0 + row4 + j) * DD + ccp] = ap[j];
  }
  // logqp
  if (w == 8 || w == 9) {
#pragma unroll
    for (int j = 0; j < 4; ++j) sTmp[row4 + j][cu] = lq[j];
  }
  __syncthreads();
  if (tid < 16) {
    float s = 0.f;
#pragma unroll
    for (int k = 0; k < 32; ++k) s += sTmp[tid][k];
    out[(size_t)TT * BB * DD + b0 + tid] = s;
  }
}

extern "C" void kernel_launch(void* const* d_in, const int* in_sizes, int n_in,
                              void* d_out, int out_size, void* d_ws,
                              size_t ws_size, hipStream_t stream) {
  const float* xs = (const float*)d_in[0];
  const float* ts = (const float*)d_in[1];
  const float* eps0 = (const float*)d_in[2];
  const float* noise = (const float*)d_in[3];
  const float* Wih = (const float*)d_in[4];
  const float* Whh = (const float*)d_in[5];
  const float* bih = (const float*)d_in[6];
  const float* bhh = (const float*)d_in[7];
  const float* encW = (const float*)d_in[8];
  const float* encb = (const float*)d_in[9];
  const float* qz0W = (const float*)d_in[10];
  const float* qz0b = (const float*)d_in[11];
  const float* fW1 = (const float*)d_in[12];
  const float* fb1 = (const float*)d_in[13];
  const float* fW2 = (const float*)d_in[14];
  const float* fb2 = (const float*)d_in[15];
  const float* fW3 = (const float*)d_in[16];
  const float* fb3 = (const float*)d_in[17];
  const float* hW1 = (const float*)d_in[18];
  const float* hb1 = (const float*)d_in[19];
  const float* hW2 = (const float*)d_in[20];
  const float* hb2 = (const float*)d_in[21];
  const float* hW3 = (const float*)d_in[22];
  const float* hb3 = (const float*)d_in[23];
  const float* gW1 = (const float*)d_in[24];
  const float* gb1 = (const float*)d_in[25];
  const float* gW2 = (const float*)d_in[26];
  const float* gb2 = (const float*)d_in[27];
  const float* projW = (const float*)d_in[28];
  const float* projb = (const float*)d_in[29];
  float* out = (float*)d_out;
  h1* ctx16 = (h1*)d_out;      // ctx[t,b,64] f16 aliases xs_hat[t,b,32] f32
  float* gtab = (float*)d_ws;  // 32*260*4 B

  k_gtab<<<32, 320, 0, stream>>>(gW1, gb1, gW2, gb2, gtab);
  k_gru<<<256, 1024, 0, stream>>>(xs, Wih, Whh, bih, bhh, encW, encb, ctx16);
  k_sde<<<256, 1024, 0, stream>>>(ts, eps0, noise, qz0W, qz0b, fW1, fb1, fW2,
                                  fb2, fW3, fb3, hW1, hb1, hW2, hb2, hW3, hb3,
                                  projW, projb, gtab, ctx16, out);
}

// Round 9
// 347.348 us; speedup vs baseline: 1.9911x; 1.0816x over previous
//
#include <hip/hip_runtime.h>

// RallyNet latent-SDE, round 9.
// k_gru: r7-proven (512 thr, (512,2), Wih/Whh pinned, encW swizzled LDS,
//        1 lgkm-only barrier/step, depth-2 xs prefetch).
// k_sde: 512 thr / 8 waves, N=32 per wave (A-frag reads serve 2 MFMAs ->
//        ~45% less LDS traffic). w0-3 f-path, w4-7 h-path; P3: w4-5
//        layer-3 (swz LDS weights) + in-register Euler-Maruyama, w6-7
//        projection + ctx staging. preP1: ctx-part of layer-1 f computed
//        in the P3 window. Depth-2 register prefetch for ctx/noise.
//        3 lgkm-only barriers/step; sC/sY16 single-buffered.
// diag-g via PWL table (d_ws). ctx[t,b,:] f16 aliases xs_hat[t,b,:] f32.

#define TT 100
#define BB 4096
#define DD 32
#define LL 32
#define CC 64
#define HH 128
#define GROW 260

typedef _Float16 h1;
typedef _Float16 h2 __attribute__((ext_vector_type(2)));
typedef _Float16 f16x8 __attribute__((ext_vector_type(8)));
typedef float f32x4 __attribute__((ext_vector_type(4)));

#define MFMA(a, b, c) __builtin_amdgcn_mfma_f32_16x16x32_f16(a, b, c, 0, 0, 0)
#define PIN(x) asm volatile("" : "+v"(x))

// lgkmcnt-only barrier: orders LDS producer->consumer without draining vmcnt
// (global prefetches/stores stay in flight across phases).
__device__ __forceinline__ void bar_lds() {
  __builtin_amdgcn_sched_barrier(0);
  asm volatile("s_waitcnt lgkmcnt(0)" ::: "memory");
  __builtin_amdgcn_s_barrier();
  asm volatile("" ::: "memory");
  __builtin_amdgcn_sched_barrier(0);
}

__device__ __forceinline__ float sigm(float x) {
  return 1.0f / (1.0f + __expf(-x));
}
__device__ __forceinline__ float tanh_(float x) {
  float e = __expf(2.0f * fminf(x, 15.0f));
  return (e - 1.0f) / (e + 1.0f);
}
__device__ __forceinline__ float splus(float x) {
  return __logf(1.0f + __expf(x));  // inputs bounded |x| << 80
}

// B-fragment of row-major W[N][K] tile (n0,k0)
__device__ __forceinline__ f16x8 bfrag(const float* __restrict__ W, int K,
                                       int n0, int k0, int lane) {
  const float* p = W + (size_t)(n0 + (lane & 15)) * K + k0 + ((lane >> 4) << 3);
  f16x8 r;
#pragma unroll
  for (int j = 0; j < 8; ++j) r[j] = (h1)p[j];
  return r;
}

// A-fragment from LDS row-major tile
__device__ __forceinline__ f16x8 afrag(const h1* base, int ld, int k0,
                                       int lane) {
  return *(const f16x8*)(base + (size_t)(lane & 15) * ld + k0 +
                         ((lane >> 4) << 3));
}

// swizzled f16 weight LDS (rows 256B; XOR bits 4-6 by row&7)
__device__ __forceinline__ void store_swz(h1* base, const float* __restrict__ W,
                                          int rows, int tid, int nthr) {
  for (int idx = tid; idx < rows * 64; idx += nthr) {
    const int n = idx >> 6, kp = idx & 63;
    float2 v = *(const float2*)(W + (size_t)n * HH + 2 * kp);
    h2 hv;
    hv[0] = (h1)v.x;
    hv[1] = (h1)v.y;
    int byte = n * 256 + kp * 4;
    byte ^= (n & 7) << 4;
    *(h2*)((char*)base + byte) = hv;
  }
}
__device__ __forceinline__ f16x8 swzfrag(const h1* base, int n0, int kt,
                                         int lane) {
  const int n = n0 + (lane & 15);
  int byte = n * 256 + kt * 64 + ((lane >> 4) << 4);
  byte ^= (n & 7) << 4;
  return *(const f16x8*)((const char*)base + byte);
}

// ---------------- g-table build ----------------
__global__ __launch_bounds__(320) void k_gtab(
    const float* __restrict__ gW1, const float* __restrict__ gb1,
    const float* __restrict__ gW2, const float* __restrict__ gb2,
    float* __restrict__ gtab) {
  const int l = blockIdx.x;
  const int e = threadIdx.x;
  if (e >= 257) return;
  const float yv = -12.f + (float)e * (24.f / 256.f);
  const float* w1 = gW1 + l * HH;
  const float* bb = gb1 + l * HH;
  const float* w2 = gW2 + l * HH;
  float a = 0.f;
#pragma unroll 4
  for (int h = 0; h < HH; ++h)
    a = fmaf(splus(fmaf(yv, w1[h], bb[h])), w2[h], a);
  gtab[l * GROW + e] = sigm(a + gb2[l]);
}

// ---------------- Kernel 1: GRU + encoder (r7-proven) ----------------
__global__ __launch_bounds__(512, 2) void k_gru(
    const float* __restrict__ xs, const float* __restrict__ Wih,
    const float* __restrict__ Whh, const float* __restrict__ bih,
    const float* __restrict__ bhh, const float* __restrict__ encW,
    const float* __restrict__ encb, h1* __restrict__ ctx16) {
  __shared__ alignas(16) h1 sH[2][16][136];
  __shared__ alignas(16) h1 sX[2][16][40];
  __shared__ alignas(16) h1 sE[64 * 128];  // swizzled encW

  const int tid = threadIdx.x;
  const int lane = tid & 63, w = tid >> 6;
  const int b0 = blockIdx.x * 16;
  const int coln = lane & 15, row4 = (lane >> 4) << 2;

  f16x8 wIH[3], wHH[3][4];
#pragma unroll
  for (int g = 0; g < 3; ++g) {
    wIH[g] = bfrag(Wih, DD, 128 * g + 16 * w, 0, lane);
#pragma unroll
    for (int kt = 0; kt < 4; ++kt)
      wHH[g][kt] = bfrag(Whh, HH, 128 * g + 16 * w, 32 * kt, lane);
  }
  const int m = 16 * w + coln;
  const float b_r = bih[m] + bhh[m];
  const float b_z = bih[128 + m] + bhh[128 + m];
  const float b_ni = bih[256 + m];
  const float b_nh = bhh[256 + m];
  const int ccE = (w >= 4) ? 16 * (w - 4) + coln : 0;
  const float bE = (w >= 4) ? encb[ccE] : 0.f;

  store_swz(sE, encW, 64, tid, 512);
  for (int i = tid; i < 16 * 136; i += 512) (&sH[0][0][0])[i] = (h1)0.0f;
  sX[0][tid >> 5][tid & 31] = (h1)xs[(size_t)b0 * DD + tid];
  float xHold = xs[(size_t)1 * BB * DD + (size_t)b0 * DD + tid];
  float hold[4] = {0.f, 0.f, 0.f, 0.f};
  __syncthreads();

  for (int t = 0; t < TT; ++t) {
    const int cur = t & 1;
    const int tf = (t + 2 < TT) ? (t + 2) : (TT - 1);
    const float xFly = xs[(size_t)tf * BB * DD + (size_t)b0 * DD + tid];

#pragma unroll
    for (int g = 0; g < 3; ++g) {
      PIN(wIH[g]);
#pragma unroll
      for (int kt = 0; kt < 4; ++kt) PIN(wHH[g][kt]);
    }

    f16x8 ax = afrag(&sX[cur][0][0], 40, 0, lane);
    f32x4 aR{b_r, b_r, b_r, b_r}, aZ{b_z, b_z, b_z, b_z};
    f32x4 aNI{b_ni, b_ni, b_ni, b_ni}, aNH{b_nh, b_nh, b_nh, b_nh};
    aR = MFMA(ax, wIH[0], aR);
    aZ = MFMA(ax, wIH[1], aZ);
    aNI = MFMA(ax, wIH[2], aNI);
#pragma unroll
    for (int kt = 0; kt < 4; ++kt) {
      f16x8 ah = afrag(&sH[cur][0][0], 136, 32 * kt, lane);
      aR = MFMA(ah, wHH[0][kt], aR);
      aZ = MFMA(ah, wHH[1][kt], aZ);
      aNH = MFMA(ah, wHH[2][kt], aNH);
    }
#pragma unroll
    for (int j = 0; j < 4; ++j) {
      float rg = sigm(aR[j]);
      float zg = sigm(aZ[j]);
      float ng = tanh_(aNI[j] + rg * aNH[j]);
      float hn = (1.0f - zg) * ng + zg * hold[j];
      hold[j] = hn;
      sH[cur ^ 1][row4 + j][m] = (h1)hn;
    }
    sX[cur ^ 1][tid >> 5][tid & 31] = (h1)xHold;
    bar_lds();  // the only barrier per step

    if (w >= 4) {
      f32x4 aE{bE, bE, bE, bE};
#pragma unroll
      for (int kt = 0; kt < 4; ++kt)
        aE = MFMA(afrag(&sH[cur ^ 1][0][0], 136, 32 * kt, lane),
                  swzfrag(sE, 16 * (w - 4), kt, lane), aE);
#pragma unroll
      for (int j = 0; j < 4; ++j)
        ctx16[((size_t)t * BB + b0 + row4 + j) * CC + ccE] = (h1)aE[j];
    }
    xHold = xFly;
  }
}

// ---------------- Kernel 2: z0 + SDE scan + projection ----------------
__global__ __launch_bounds__(512, 2) void k_sde(
    const float* __restrict__ ts, const float* __restrict__ eps0,
    const float* __restrict__ noise, const float* __restrict__ qz0W,
    const float* __restrict__ qz0b, const float* __restrict__ fW1,
    const float* __restrict__ fb1, const float* __restrict__ fW2,
    const float* __restrict__ fb2, const float* __restrict__ fW3,
    const float* __restrict__ fb3, const float* __restrict__ hW1,
    const float* __restrict__ hb1, const float* __restrict__ hW2,
    const float* __restrict__ hb2, const float* __restrict__ hW3,
    const float* __restrict__ hb3, const float* __restrict__ projW,
    const float* __restrict__ projb, const float* __restrict__ gtab,
    const h1* __restrict__ ctx16, float* __restrict__ out) {
  __shared__ alignas(16) h1 sC[16][72];       // ctx(t) then ctx(t+1), single buf
  __shared__ alignas(16) h1 sY16[16][40];     // y, single buf
  __shared__ alignas(16) h1 sA1[16][136], sB1[16][136];
  __shared__ alignas(16) h1 sA2[16][136], sB2[16][136];
  __shared__ alignas(16) h1 sW3f[32 * 128], sW3h[32 * 128];
  __shared__ float sG[32][GROW];
  __shared__ float sDt[128], sSq[128];
  __shared__ float sTmp[16][33];

  const int tid = threadIdx.x;
  const int lane = tid & 63, w = tid >> 6;
  const int b0 = blockIdx.x * 16;
  const int coln = lane & 15, row4 = (lane >> 4) << 2;
  const bool isF = (w < 4);
  const int t2 = isF ? w : (w - 4);           // tile-pair 0..3
  const int colA = 32 * t2 + coln, colB = colA + 16;

  // pinned weights: f-waves 14 frags, h-waves 10 (+1 proj on w6-7)
  f16x8 wL1a[3], wL1b[3], wL2a[4], wL2b[4], wPj;
  if (isF) {
#pragma unroll
    for (int kt = 0; kt < 3; ++kt) {
      wL1a[kt] = bfrag(fW1, 96, 32 * t2, 32 * kt, lane);
      wL1b[kt] = bfrag(fW1, 96, 32 * t2 + 16, 32 * kt, lane);
    }
#pragma unroll
    for (int kt = 0; kt < 4; ++kt) {
      wL2a[kt] = bfrag(fW2, HH, 32 * t2, 32 * kt, lane);
      wL2b[kt] = bfrag(fW2, HH, 32 * t2 + 16, 32 * kt, lane);
    }
  } else {
    wL1a[0] = bfrag(hW1, 32, 32 * t2, 0, lane);
    wL1b[0] = bfrag(hW1, 32, 32 * t2 + 16, 0, lane);
#pragma unroll
    for (int kt = 0; kt < 4; ++kt) {
      wL2a[kt] = bfrag(hW2, HH, 32 * t2, 32 * kt, lane);
      wL2b[kt] = bfrag(hW2, HH, 32 * t2 + 16, 32 * kt, lane);
    }
  }
  const float bL1a = isF ? fb1[colA] : hb1[colA];
  const float bL1b = isF ? fb1[colB] : hb1[colB];
  const float bL2a = isF ? fb2[colA] : hb2[colA];
  const float bL2b = isF ? fb2[colB] : hb2[colB];

  // P3 roles
  float bF3 = 0.f, bH3 = 0.f, bPj = 0.f;
  int cu = 0, ccp = 0, srow = 0, scol = 0;
  if (w == 4 || w == 5) {
    cu = 16 * (w - 4) + coln;
    bF3 = fb3[cu];
    bH3 = hb3[cu];
  } else if (w >= 6) {
    ccp = 16 * (w - 6) + coln;
    wPj = bfrag(projW, LL, 16 * (w - 6), 0, lane);
    bPj = projb[ccp];
    const int sidx = tid - 384;  // 0..127
    srow = sidx >> 3;
    scol = (sidx & 7) * 8;
  }

  store_swz(sW3f, fW3, 32, tid, 512);
  store_swz(sW3h, hW3, 32, tid, 512);
  for (int i = tid; i < 32 * GROW; i += 512) (&sG[0][0])[i] = gtab[i];
  if (tid < TT - 1) {
    float d = ts[tid + 1] - ts[tid];
    sDt[tid] = d;
    sSq[tid] = __fsqrt_rn(d);
  }
  // stage ctx(0)
  *(h2*)&sC[tid >> 5][2 * (tid & 31)] =
      *(const h2*)(ctx16 + (size_t)(b0 + (tid >> 5)) * CC + 2 * (tid & 31));
  __syncthreads();

  // z0 = mean + exp(logstd)*eps0 (all threads, one (row,col) each)
  {
    const int sr = tid >> 5, sc = tid & 31;
    float m0 = qz0b[sc], s0 = qz0b[32 + sc];
    const float* qm = qz0W + sc * 64;
    const float* qs = qz0W + (32 + sc) * 64;
#pragma unroll 4
    for (int k = 0; k < 64; ++k) {
      float cv = (float)sC[sr][k];
      m0 = fmaf(qm[k], cv, m0);
      s0 = fmaf(qs[k], cv, s0);
    }
    float z = fmaf(__expf(s0), eps0[(size_t)(b0 + sr) * LL + sc], m0);
    sTmp[sr][sc] = z;
    sY16[sr][sc] = (h1)z;
  }
  // prefetch primers (depth-2 pipelines)
  f16x8 cHold;
  if (w >= 6)
    cHold = *(const f16x8*)(ctx16 + ((size_t)1 * BB + b0 + srow) * CC + scol);
  float nHold[4] = {0.f, 0.f, 0.f, 0.f};
  if (w == 4 || w == 5) {
#pragma unroll
    for (int j = 0; j < 4; ++j)
      nHold[j] = noise[(size_t)(b0 + row4 + j) * LL + cu];
  }
  __syncthreads();

  float yreg[4] = {0.f, 0.f, 0.f, 0.f}, lq[4] = {0.f, 0.f, 0.f, 0.f};
  if (w == 4 || w == 5) {
#pragma unroll
    for (int j = 0; j < 4; ++j) yreg[j] = sTmp[row4 + j][cu];
  }

  // preP1 for t=0 (ctx part of layer-1 f)
  f32x4 accA{bL1a, bL1a, bL1a, bL1a}, accB{bL1b, bL1b, bL1b, bL1b};
  if (isF) {
    f16x8 c0 = afrag(&sC[0][0], 72, 0, lane);
    f16x8 c1 = afrag(&sC[0][0], 72, 32, lane);
    accA = MFMA(c0, wL1a[1], accA);
    accA = MFMA(c1, wL1a[2], accA);
    accB = MFMA(c0, wL1b[1], accB);
    accB = MFMA(c1, wL1b[2], accB);
  }

  for (int t = 0; t < TT - 1; ++t) {
    // depth-2 prefetch issues (consumed next iteration / late this one)
    f16x8 cFly;
    if (w >= 6) {
      const int tc = (t + 2 <= TT - 1) ? t + 2 : TT - 1;
      cFly = *(const f16x8*)(ctx16 + ((size_t)tc * BB + b0 + srow) * CC + scol);
    }
    float nFly[4];
    if (w == 4 || w == 5) {
      const int tn = (t + 1 < TT - 1) ? t + 1 : TT - 2;
#pragma unroll
      for (int j = 0; j < 4; ++j)
        nFly[j] = noise[((size_t)tn * BB + b0 + row4 + j) * LL + cu];
    }

    if (isF) {
#pragma unroll
      for (int kt = 0; kt < 3; ++kt) {
        PIN(wL1a[kt]);
        PIN(wL1b[kt]);
      }
    } else {
      PIN(wL1a[0]);
      PIN(wL1b[0]);
    }
#pragma unroll
    for (int kt = 0; kt < 4; ++kt) {
      PIN(wL2a[kt]);
      PIN(wL2b[kt]);
    }
    if (w >= 6) PIN(wPj);

    // ---- P1: finish layer 1 (y part only for f; full for h) ----
    f16x8 aY = afrag(&sY16[0][0], 40, 0, lane);
    if (isF) {
      accA = MFMA(aY, wL1a[0], accA);
      accB = MFMA(aY, wL1b[0], accB);
#pragma unroll
      for (int j = 0; j < 4; ++j) {
        sA1[row4 + j][colA] = (h1)splus(accA[j]);
        sA1[row4 + j][colB] = (h1)splus(accB[j]);
      }
    } else {
      f32x4 hA{bL1a, bL1a, bL1a, bL1a}, hB{bL1b, bL1b, bL1b, bL1b};
      hA = MFMA(aY, wL1a[0], hA);
      hB = MFMA(aY, wL1b[0], hB);
#pragma unroll
      for (int j = 0; j < 4; ++j) {
        sB1[row4 + j][colA] = (h1)splus(hA[j]);
        sB1[row4 + j][colB] = (h1)splus(hB[j]);
      }
    }
    bar_lds();  // BAR1

    // ---- P2: layer 2 (each A-frag read feeds 2 MFMAs) ----
    {
      const h1* src = isF ? &sA1[0][0] : &sB1[0][0];
      h1* dst = isF ? &sA2[0][0] : &sB2[0][0];
      f32x4 pA{bL2a, bL2a, bL2a, bL2a}, pB{bL2b, bL2b, bL2b, bL2b};
#pragma unroll
      for (int kt = 0; kt < 4; ++kt) {
        f16x8 a = afrag(src, 136, 32 * kt, lane);
        pA = MFMA(a, wL2a[kt], pA);
        pB = MFMA(a, wL2b[kt], pB);
      }
#pragma unroll
      for (int j = 0; j < 4; ++j) {
        dst[(size_t)(row4 + j) * 136 + colA] = (h1)splus(pA[j]);
        dst[(size_t)(row4 + j) * 136 + colB] = (h1)splus(pB[j]);
      }
    }
    if (w >= 6) {  // stage ctx(t+1) (loaded ~1 step ago; no vmcnt stall)
      *(f16x8*)&sC[srow][scol] = cHold;
      cHold = cFly;
    }
    bar_lds();  // BAR2

    // ---- P3 ----
    if (isF) {
      // preP1 for t+1 from ctx(t+1) just staged
      f16x8 c0 = afrag(&sC[0][0], 72, 0, lane);
      f16x8 c1 = afrag(&sC[0][0], 72, 32, lane);
      accA = f32x4{bL1a, bL1a, bL1a, bL1a};
      accB = f32x4{bL1b, bL1b, bL1b, bL1b};
      accA = MFMA(c0, wL1a[1], accA);
      accA = MFMA(c1, wL1a[2], accA);
      accB = MFMA(c0, wL1b[1], accB);
      accB = MFMA(c1, wL1b[2], accB);
    } else if (w < 6) {
      // layer 3 f+h for cols cu, then in-register Euler-Maruyama
      f32x4 aF{bF3, bF3, bF3, bF3}, aH{bH3, bH3, bH3, bH3};
#pragma unroll
      for (int kt = 0; kt < 4; ++kt) {
        aF = MFMA(afrag(&sA2[0][0], 136, 32 * kt, lane),
                  swzfrag(sW3f, 16 * (w - 4), kt, lane), aF);
        aH = MFMA(afrag(&sB2[0][0], 136, 32 * kt, lane),
                  swzfrag(sW3h, 16 * (w - 4), kt, lane), aH);
      }
      const float dtv = sDt[t], sqdt = sSq[t];
      const float* g = sG[cu];
#pragma unroll
      for (int j = 0; j < 4; ++j) {
        float p = fminf(fmaxf(fmaf(yreg[j], 32.f / 3.f, 128.f), 0.f), 255.999f);
        const int i = (int)p;
        const float fr = p - (float)i;
        const float gv = fmaf(g[i + 1] - g[i], fr, g[i]);
        const float uv = (aF[j] - aH[j]) / gv;
        lq[j] = fmaf(0.5f * uv * uv, dtv, lq[j]);
        yreg[j] = fmaf(aF[j], dtv, yreg[j]) + gv * sqdt * nHold[j];
        sY16[row4 + j][cu] = (h1)yreg[j];
      }
#pragma unroll
      for (int j = 0; j < 4; ++j) nHold[j] = nFly[j];
    } else {
      // projection of zs[t] (aY captured in P1)
      f32x4 ap{bPj, bPj, bPj, bPj};
      ap = MFMA(aY, wPj, ap);
#pragma unroll
      for (int j = 0; j < 4; ++j)
        out[((size_t)t * BB + b0 + row4 + j) * DD + ccp] = ap[j];
    }
    bar_lds();  // BAR3
  }

  // final projection xs_hat[99]
  if (w >= 6) {
    f16x8 aYf = afrag(&sY16[0][0], 40, 0, lane);
    f32x4 ap{bPj, bPj, bPj, bPj};
    ap = MFMA(aYf, wPj, ap);
#pragma unroll
    for (int j = 0; j < 4; ++j)
      out[((size_t)(TT - 1) * BB + b0 + row4 + j) * DD + ccp] = ap[j];
  }
  // logqp reduce
  if (w == 4 || w == 5) {
#pragma unroll
    for (int j = 0; j < 4; ++j) sTmp[row4 + j][cu] = lq[j];
  }
  __syncthreads();
  if (tid < 16) {
    float s = 0.f;
#pragma unroll
    for (int k = 0; k < 32; ++k) s += sTmp[tid][k];
    out[(size_t)TT * BB * DD + b0 + tid] = s;
  }
}

extern "C" void kernel_launch(void* const* d_in, const int* in_sizes, int n_in,
                              void* d_out, int out_size, void* d_ws,
                              size_t ws_size, hipStream_t stream) {
  const float* xs = (const float*)d_in[0];
  const float* ts = (const float*)d_in[1];
  const float* eps0 = (const float*)d_in[2];
  const float* noise = (const float*)d_in[3];
  const float* Wih = (const float*)d_in[4];
  const float* Whh = (const float*)d_in[5];
  const float* bih = (const float*)d_in[6];
  const float* bhh = (const float*)d_in[7];
  const float* encW = (const float*)d_in[8];
  const float* encb = (const float*)d_in[9];
  const float* qz0W = (const float*)d_in[10];
  const float* qz0b = (const float*)d_in[11];
  const float* fW1 = (const float*)d_in[12];
  const float* fb1 = (const float*)d_in[13];
  const float* fW2 = (const float*)d_in[14];
  const float* fb2 = (const float*)d_in[15];
  const float* fW3 = (const float*)d_in[16];
  const float* fb3 = (const float*)d_in[17];
  const float* hW1 = (const float*)d_in[18];
  const float* hb1 = (const float*)d_in[19];
  const float* hW2 = (const float*)d_in[20];
  const float* hb2 = (const float*)d_in[21];
  const float* hW3 = (const float*)d_in[22];
  const float* hb3 = (const float*)d_in[23];
  const float* gW1 = (const float*)d_in[24];
  const float* gb1 = (const float*)d_in[25];
  const float* gW2 = (const float*)d_in[26];
  const float* gb2 = (const float*)d_in[27];
  const float* projW = (const float*)d_in[28];
  const float* projb = (const float*)d_in[29];
  float* out = (float*)d_out;
  h1* ctx16 = (h1*)d_out;      // ctx[t,b,64] f16 aliases xs_hat[t,b,32] f32
  float* gtab = (float*)d_ws;  // 32*260*4 B

  k_gtab<<<32, 320, 0, stream>>>(gW1, gb1, gW2, gb2, gtab);
  k_gru<<<256, 512, 0, stream>>>(xs, Wih, Whh, bih, bhh, encW, encb, ctx16);
  k_sde<<<256, 512, 0, stream>>>(ts, eps0, noise, qz0W, qz0b, fW1, fb1, fW2,
                                 fb2, fW3, fb3, hW1, hb1, hW2, hb2, hW3, hb3,
                                 projW, projb, gtab, ctx16, out);
}